// Round 1
// baseline (1907.930 us; speedup 1.0000x reference)
//
#include <hip/hip_runtime.h>

// Problem constants
#define BB 32
#define NNODE 512
#define EE 128
#define CAP 786432  // edge capacity per stream (expected ~419K, sigma ~630)

// ws layout (floats):
//  wh   : 4*32*512*128 = 8388608   (4 streams: s1fwd, s1rev, s2fwd, s2rev)
//  whg  : 8388608                  (aliased as xp[2][16384][192] before graph)
//  x    : 2*32*512*128 = 4194304
//  ah1  : 65536,  ah2: 65536, mid: 8192, e12: 4096
//  ints: starts 65536, counts 65536, fillpos 32768, cursors 64, edges 4*CAP
//  total ~97.7 MB

__device__ __forceinline__ float sigm(float x) { return 1.0f / (1.0f + __expf(-x)); }
__device__ __forceinline__ float tanh_f(float x) {
  x = fminf(20.f, fmaxf(-20.f, x));
  float t = __expf(-2.f * x);
  return (1.f - t) / (1.f + t);
}

#define FMA4(ACC, OFF, RV, W)                                                  \
  ACC[(OFF) + 0] = fmaf((RV), (W).x, ACC[(OFF) + 0]);                          \
  ACC[(OFF) + 1] = fmaf((RV), (W).y, ACC[(OFF) + 1]);                          \
  ACC[(OFF) + 2] = fmaf((RV), (W).z, ACC[(OFF) + 2]);                          \
  ACC[(OFF) + 3] = fmaf((RV), (W).w, ACC[(OFF) + 3]);

// ---------------------------------------------------------------------------
// x[:, :, 0:64] = relu(LIT @ W_lit);  xp = SEM @ gru_k + gru_b[0]
// grid 1024 x 64.  bid>>1 = 64-row block, bid&1 = col half.
__global__ __launch_bounds__(64, 1) void k_data(
    const float* __restrict__ lit1, const float* __restrict__ sem1,
    const float* __restrict__ lit2, const float* __restrict__ sem2,
    const float* __restrict__ wl1, const float* __restrict__ gk1,
    const float* __restrict__ gb1, const float* __restrict__ wl2,
    const float* __restrict__ gk2, const float* __restrict__ gb2,
    float* __restrict__ x, float* __restrict__ xp) {
  __shared__ float stage[64 * 65];
  int bid = blockIdx.x;
  int rowblk = bid >> 1, half = bid & 1;
  int grow0 = rowblk * 64;
  int side = grow0 >> 14;
  int lrow0 = grow0 & 16383;
  const float* lit = side ? lit2 : lit1;
  const float* sem = side ? sem2 : sem1;
  const float* wl = side ? wl2 : wl1;
  const float* gk = side ? gk2 : gk1;
  const float* gb = side ? gb2 : gb1;
  int tid = threadIdx.x;
  int grow = grow0 + tid;

  // ---- literal matmul: 64 rows x 32 cols (this half) ----
  {
    const float4* lit4 = (const float4*)(lit + (size_t)lrow0 * 64);
#pragma unroll
    for (int p = 0; p < 16; ++p) {
      int s = p * 64 + tid;
      int r = s >> 4, q = s & 15;
      float4 v = lit4[r * 16 + q];
      stage[r * 65 + 4 * q + 0] = v.x;
      stage[r * 65 + 4 * q + 1] = v.y;
      stage[r * 65 + 4 * q + 2] = v.z;
      stage[r * 65 + 4 * q + 3] = v.w;
    }
    float acc[32];
#pragma unroll
    for (int c = 0; c < 32; ++c) acc[c] = 0.f;
    const float4* wl4 = (const float4*)wl;  // [64][16] f4
    for (int i = 0; i < 64; ++i) {
      float rv = stage[tid * 65 + i];
#pragma unroll
      for (int c4 = 0; c4 < 8; ++c4) {
        float4 w = wl4[i * 16 + half * 8 + c4];
        FMA4(acc, 4 * c4, rv, w)
      }
    }
    float4* x4 = (float4*)x;
#pragma unroll
    for (int c4 = 0; c4 < 8; ++c4) {
      float4 o;
      o.x = fmaxf(acc[4 * c4 + 0], 0.f);
      o.y = fmaxf(acc[4 * c4 + 1], 0.f);
      o.z = fmaxf(acc[4 * c4 + 2], 0.f);
      o.w = fmaxf(acc[4 * c4 + 3], 0.f);
      x4[(size_t)grow * 32 + half * 8 + c4] = o;
    }
  }
  // ---- semantic input projection: 64 rows x 96 cols (this half) ----
  {
    const float4* sem4 = (const float4*)(sem + (size_t)lrow0 * 64);
#pragma unroll
    for (int p = 0; p < 16; ++p) {
      int s = p * 64 + tid;
      int r = s >> 4, q = s & 15;
      float4 v = sem4[r * 16 + q];
      stage[r * 65 + 4 * q + 0] = v.x;
      stage[r * 65 + 4 * q + 1] = v.y;
      stage[r * 65 + 4 * q + 2] = v.z;
      stage[r * 65 + 4 * q + 3] = v.w;
    }
    float acc2[96];
#pragma unroll
    for (int c = 0; c < 96; ++c) acc2[c] = gb[half * 96 + c];  // bias row 0
    const float4* gk4 = (const float4*)gk;  // [64][48] f4
    for (int i = 0; i < 64; ++i) {
      float rv = stage[tid * 65 + i];
#pragma unroll
      for (int c4 = 0; c4 < 24; ++c4) {
        float4 w = gk4[i * 48 + half * 24 + c4];
        FMA4(acc2, 4 * c4, rv, w)
      }
    }
    float4* xp4 = (float4*)xp;
#pragma unroll
    for (int c4 = 0; c4 < 24; ++c4) {
      float4 o;
      o.x = acc2[4 * c4 + 0];
      o.y = acc2[4 * c4 + 1];
      o.z = acc2[4 * c4 + 2];
      o.w = acc2[4 * c4 + 3];
      xp4[(size_t)grow * 48 + half * 24 + c4] = o;
    }
  }
}

// ---------------------------------------------------------------------------
// GRU scan (Keras reset_after). One wave per (side,batch). 512 sequential steps.
// grid 64 x 64
__global__ __launch_bounds__(64, 1) void k_gru(
    const float* __restrict__ xp, const float* __restrict__ rk1,
    const float* __restrict__ b1, const float* __restrict__ rk2,
    const float* __restrict__ b2, float* __restrict__ x) {
  int blk = blockIdx.x;
  int side = blk >> 5, b = blk & 31;
  int j = threadIdx.x;
  const float* rk = side ? rk2 : rk1;
  const float* bb = side ? b2 : b1;
  float wz[64], wr[64], wv[64];
#pragma unroll
  for (int i = 0; i < 64; ++i) {
    wz[i] = rk[i * 192 + j];
    wr[i] = rk[i * 192 + 64 + j];
    wv[i] = rk[i * 192 + 128 + j];
  }
  float bz = bb[192 + j], brr = bb[192 + 64 + j], bv = bb[192 + 128 + j];
  __shared__ float hs[64];
  hs[j] = 0.f;
  float hj = 0.f;
  const float* xpr = xp + (size_t)(side * 16384 + b * 512) * 192;
  float* xrow = x + (size_t)(side * 16384 + b * 512) * 128;
  float cxz = xpr[j], cxr = xpr[64 + j], cxv = xpr[128 + j];
  for (int t = 0; t < 512; ++t) {
    float az = 0.f, ar = 0.f, av = 0.f;
    const float4* h4 = (const float4*)hs;
#pragma unroll
    for (int c = 0; c < 16; ++c) {
      float4 h = h4[c];
      az = fmaf(h.x, wz[4 * c + 0], az);
      az = fmaf(h.y, wz[4 * c + 1], az);
      az = fmaf(h.z, wz[4 * c + 2], az);
      az = fmaf(h.w, wz[4 * c + 3], az);
      ar = fmaf(h.x, wr[4 * c + 0], ar);
      ar = fmaf(h.y, wr[4 * c + 1], ar);
      ar = fmaf(h.z, wr[4 * c + 2], ar);
      ar = fmaf(h.w, wr[4 * c + 3], ar);
      av = fmaf(h.x, wv[4 * c + 0], av);
      av = fmaf(h.y, wv[4 * c + 1], av);
      av = fmaf(h.z, wv[4 * c + 2], av);
      av = fmaf(h.w, wv[4 * c + 3], av);
    }
    float nxz = 0.f, nxr = 0.f, nxv = 0.f;
    if (t + 1 < 512) {
      const float* p = xpr + (size_t)(t + 1) * 192;
      nxz = p[j];
      nxr = p[64 + j];
      nxv = p[128 + j];
    }
    float z = sigm(cxz + az + bz);
    float r = sigm(cxr + ar + brr);
    float hh = tanh_f(cxv + r * (av + bv));
    hj = fmaf(z, hj - hh, hh);  // z*h + (1-z)*hh
    xrow[(size_t)t * 128 + 64 + j] = hj;
    hs[j] = hj;  // single wave: LDS ops in program order, no barrier needed
    cxz = nxz;
    cxr = nxr;
    cxv = nxv;
  }
}

// ---------------------------------------------------------------------------
// CSR build. grid 32768 x 128. Row = (side, b, iA) of A.
__global__ __launch_bounds__(128, 1) void k_csr_count(
    const float* __restrict__ A1, const float* __restrict__ A2,
    int* __restrict__ starts, int* __restrict__ counts,
    int* __restrict__ cursors) {
  int row = blockIdx.x;
  int s = row >> 14, br = row & 16383;
  int b = br >> 9;
  const float* A = s ? A2 : A1;
  const float4* Ar = (const float4*)(A + (size_t)br * 512);
  int t = threadIdx.x;
  float4 v = Ar[t];
  int* crev = counts + (2 * s + 1) * 16384 + b * 512;
  int cnt = 0;
  if (v.x != 0.f) { cnt++; atomicAdd(&crev[4 * t + 0], 1); }
  if (v.y != 0.f) { cnt++; atomicAdd(&crev[4 * t + 1], 1); }
  if (v.z != 0.f) { cnt++; atomicAdd(&crev[4 * t + 2], 1); }
  if (v.w != 0.f) { cnt++; atomicAdd(&crev[4 * t + 3], 1); }
  for (int off = 32; off; off >>= 1) cnt += __shfl_xor(cnt, off, 64);
  __shared__ int red[2];
  if ((t & 63) == 0) red[t >> 6] = cnt;
  __syncthreads();
  if (t == 0) {
    int tot = red[0] + red[1];
    counts[2 * s * 16384 + br] = tot;
    starts[2 * s * 16384 + br] = atomicAdd(&cursors[2 * s], tot);
  }
}

__global__ void k_csr_alloc(int* __restrict__ starts, int* __restrict__ counts,
                            int* __restrict__ fillpos,
                            int* __restrict__ cursors) {
  int tid = blockIdx.x * 256 + threadIdx.x;
  if (tid >= 32768) return;
  int s = tid >> 14, loc = tid & 16383;
  int rrow = (2 * s + 1) * 16384 + loc;
  starts[rrow] = atomicAdd(&cursors[2 * s + 1], counts[rrow]);
  fillpos[tid] = 0;
}

__global__ __launch_bounds__(128, 1) void k_csr_fill(
    const float* __restrict__ A1, const float* __restrict__ A2,
    const int* __restrict__ starts, int* __restrict__ fillpos,
    int* __restrict__ edges) {
  int row = blockIdx.x;
  int s = row >> 14, br = row & 16383;
  int b = br >> 9, iA = br & 511;
  const float* A = s ? A2 : A1;
  const float4* Ar = (const float4*)(A + (size_t)br * 512);
  __shared__ int lcnt;
  if (threadIdx.x == 0) lcnt = 0;
  __syncthreads();
  int t = threadIdx.x;
  float4 v = Ar[t];
  float vv[4] = {v.x, v.y, v.z, v.w};
  int fstart = starts[2 * s * 16384 + br];
  int* efwd = edges + (size_t)(2 * s) * CAP;
  int* erev = edges + (size_t)(2 * s + 1) * CAP;
  const int* rstart = starts + (2 * s + 1) * 16384 + b * 512;
  int* fpos = fillpos + s * 16384 + b * 512;
#pragma unroll
  for (int e = 0; e < 4; ++e) {
    if (vv[e] != 0.f) {
      int jj = 4 * t + e;
      int off = atomicAdd(&lcnt, 1);
      int fi = fstart + off;
      if (fi < CAP) efwd[fi] = jj;
      int p = atomicAdd(&fpos[jj], 1);
      int ri = rstart[jj] + p;
      if (ri < CAP) erev[ri] = iA;
    }
  }
}

// ---------------------------------------------------------------------------
// wh[st] = relu(x[side(st)]). grid 8192 x 256 over f4.
__global__ void k_init(const float* __restrict__ x, float* __restrict__ wh) {
  int idx = blockIdx.x * 256 + threadIdx.x;
  int st = idx >> 19;  // 524288 f4 per stream
  int loc = idx & 524287;
  int side = st >> 1;
  float4 v = ((const float4*)x)[(size_t)side * 524288 + loc];
  v.x = fmaxf(v.x, 0.f);
  v.y = fmaxf(v.y, 0.f);
  v.z = fmaxf(v.z, 0.f);
  v.w = fmaxf(v.w, 0.f);
  ((float4*)wh)[idx] = v;
}

// ---------------------------------------------------------------------------
// whg = wh @ W_g;  ah1 = wh@a1_w + a1_b;  ah2 = wh@a2_w + a2_b
// grid 1024 x 64; one wave = 64 rows, acc[128] in regs, W_g via uniform loads.
__global__ __launch_bounds__(64, 1) void k_whg(
    const float* __restrict__ wh, const float* __restrict__ Wg,
    const float* __restrict__ a1w, const float* __restrict__ a1b,
    const float* __restrict__ a2w, const float* __restrict__ a2b,
    float* __restrict__ whg, float* __restrict__ ah1, float* __restrict__ ah2) {
  __shared__ float stage[64 * 129];
  int rowbase = blockIdx.x * 64;
  int tid = threadIdx.x;
  const float4* wh4 = (const float4*)(wh + (size_t)rowbase * 128);
#pragma unroll
  for (int p = 0; p < 32; ++p) {
    int s = p * 64 + tid;
    int r = s >> 5, q = s & 31;
    float4 v = wh4[r * 32 + q];
    stage[r * 129 + 4 * q + 0] = v.x;
    stage[r * 129 + 4 * q + 1] = v.y;
    stage[r * 129 + 4 * q + 2] = v.z;
    stage[r * 129 + 4 * q + 3] = v.w;
  }
  float acc[128];
#pragma unroll
  for (int c = 0; c < 128; ++c) acc[c] = 0.f;
  float p1 = a1b[0], p2 = a2b[0];
  const float4* Wg4 = (const float4*)Wg;  // [128][32] f4
  for (int i = 0; i < 128; ++i) {
    float rv = stage[tid * 129 + i];
    p1 = fmaf(rv, a1w[i], p1);
    p2 = fmaf(rv, a2w[i], p2);
#pragma unroll
    for (int c4 = 0; c4 < 32; ++c4) {
      float4 w = Wg4[i * 32 + c4];
      FMA4(acc, 4 * c4, rv, w)
    }
  }
  int grow = rowbase + tid;
  float4* o4 = (float4*)(whg + (size_t)grow * 128);
#pragma unroll
  for (int c4 = 0; c4 < 32; ++c4) {
    float4 o;
    o.x = acc[4 * c4 + 0];
    o.y = acc[4 * c4 + 1];
    o.z = acc[4 * c4 + 2];
    o.w = acc[4 * c4 + 3];
    o4[c4] = o;
  }
  ah1[grow] = p1;
  ah2[grow] = p2;
}

// ---------------------------------------------------------------------------
// Per-row edge softmax + aggregate + elu update. grid 65536 x 128.
__global__ __launch_bounds__(128, 1) void k_attn(
    float* __restrict__ wh, const float* __restrict__ whg,
    const float* __restrict__ ah1, const float* __restrict__ ah2,
    const int* __restrict__ starts, const int* __restrict__ counts,
    const int* __restrict__ edges) {
  int row = blockIdx.x;
  int st = row >> 14;
  int base = row & ~511;  // row index of (st,b) block start
  int t = threadIdx.x;
  __shared__ int jl[512];
  __shared__ float el[512];
  __shared__ float red[2];
  int start = starts[row], cnt = counts[row];
  const int* ed = edges + (size_t)st * CAP + start;
  float a1v = ah1[row];
  const float* ah2b = ah2 + base;
  float lmax = -1e30f;
  for (int k = t; k < cnt; k += 128) {
    int jj = ed[k];
    float e = a1v + ah2b[jj];
    e = e >= 0.f ? e : 0.2f * e;  // leaky_relu 0.2
    jl[k] = jj;
    el[k] = e;
    lmax = fmaxf(lmax, e);
  }
  for (int off = 32; off; off >>= 1) lmax = fmaxf(lmax, __shfl_xor(lmax, off, 64));
  if ((t & 63) == 0) red[t >> 6] = lmax;
  __syncthreads();
  float m = fmaxf(red[0], red[1]);
  __syncthreads();
  float lsum = 0.f;
  for (int k = t; k < cnt; k += 128) {
    float w = __expf(el[k] - m);
    el[k] = w;
    lsum += w;
  }
  for (int off = 32; off; off >>= 1) lsum += __shfl_xor(lsum, off, 64);
  if ((t & 63) == 0) red[t >> 6] = lsum;
  __syncthreads();
  float Z = red[0] + red[1];
  float inv = cnt > 0 ? 1.0f / Z : 0.f;
  float acc = 0.f;
  const float* wgb = whg + (size_t)base * 128;
  for (int k = 0; k < cnt; ++k) {
    acc = fmaf(el[k], wgb[(size_t)jl[k] * 128 + t], acc);
  }
  acc *= inv;
  float v = wh[(size_t)row * 128 + t] + acc;
  wh[(size_t)row * 128 + t] = v > 0.f ? v : __expf(v) - 1.f;  // elu
}

// ---------------------------------------------------------------------------
// mid[side][b][c] = sum_i (wh[2s][b][i][c] + wh[2s+1][b][i][c]). grid 512x256.
__global__ void k_mid(const float* __restrict__ wh, float* __restrict__ mid) {
  int blk = blockIdx.x;
  int side = blk >> 8, b = (blk >> 3) & 31, ch = blk & 7;
  int t = threadIdx.x;
  int c = t & 127, hh = t >> 7;
  float sum = 0.f;
  size_t b0 = ((size_t)(2 * side) * 16384 + b * 512) * 128;
  size_t b1 = ((size_t)(2 * side + 1) * 16384 + b * 512) * 128;
  for (int q = 0; q < 32; ++q) {
    int i = ch * 64 + hh * 32 + q;
    sum += wh[b0 + (size_t)i * 128 + c];
    sum += wh[b1 + (size_t)i * 128 + c];
  }
  atomicAdd(&mid[(side * 32 + b) * 128 + c], sum);
}

__global__ void k_out(const float* __restrict__ mid,
                      const float* __restrict__ Wout,
                      const float* __restrict__ bout, float* __restrict__ e12) {
  int sb = blockIdx.x;  // 0..63  (side*32+b)
  int o = threadIdx.x;  // 0..63
  const float* m = mid + sb * 128;
  float acc = bout[o];
  for (int k = 0; k < 128; ++k) acc = fmaf(m[k], Wout[k * 64 + o], acc);
  e12[sb * 64 + o] = acc;
}

__global__ void k_cos(const float* __restrict__ e12, float* __restrict__ out) {
  int b = threadIdx.x;
  if (b >= 32) return;
  const float* e1 = e12 + b * 64;
  const float* e2 = e12 + 2048 + b * 64;
  float d = 0.f, n1 = 0.f, n2 = 0.f;
  for (int o = 0; o < 64; ++o) {
    float a = e1[o], c = e2[o];
    d = fmaf(a, c, d);
    n1 = fmaf(a, a, n1);
    n2 = fmaf(c, c, n2);
  }
  float nn = fmaxf(sqrtf(n1), 1e-12f) * fmaxf(sqrtf(n2), 1e-12f);
  out[b] = 0.5f * (1.f + d / nn);
}

// ---------------------------------------------------------------------------
extern "C" void kernel_launch(void* const* d_in, const int* in_sizes, int n_in,
                              void* d_out, int out_size, void* d_ws,
                              size_t ws_size, hipStream_t stream) {
  const float* CFG1 = (const float*)d_in[0];
  const float* LIT1 = (const float*)d_in[2];
  const float* SEM1 = (const float*)d_in[3];
  const float* CFG2 = (const float*)d_in[4];
  const float* LIT2 = (const float*)d_in[6];
  const float* SEM2 = (const float*)d_in[7];
  const float* WL1 = (const float*)d_in[8];
  const float* GK1 = (const float*)d_in[9];
  const float* GRK1 = (const float*)d_in[10];
  const float* GB1 = (const float*)d_in[11];
  const float* WL2 = (const float*)d_in[12];
  const float* GK2 = (const float*)d_in[13];
  const float* GRK2 = (const float*)d_in[14];
  const float* GB2 = (const float*)d_in[15];
  const float* A1W = (const float*)d_in[16];
  const float* A1B = (const float*)d_in[17];
  const float* A2W = (const float*)d_in[18];
  const float* A2B = (const float*)d_in[19];
  const float* WG = (const float*)d_in[20];
  const float* WOUT = (const float*)d_in[21];
  const float* BOUT = (const float*)d_in[22];

  float* ws = (float*)d_ws;
  float* wh = ws;                    // 8388608
  float* whg = wh + 8388608;         // 8388608 (xp aliases)
  float* xp = whg;
  float* x = whg + 8388608;          // 4194304
  float* ah1 = x + 4194304;          // 65536
  float* ah2 = ah1 + 65536;          // 65536
  float* mid = ah2 + 65536;          // 8192
  float* e12 = mid + 8192;           // 4096
  int* starts = (int*)(e12 + 4096);  // 65536
  int* counts = starts + 65536;      // 65536
  int* fillpos = counts + 65536;     // 32768
  int* cursors = fillpos + 32768;    // 64
  int* edges = cursors + 64;         // 4*CAP

  hipMemsetAsync(starts, 0, (size_t)(65536 + 65536 + 32768 + 64) * 4, stream);
  hipMemsetAsync(mid, 0, 8192 * 4, stream);

  k_data<<<1024, 64, 0, stream>>>(LIT1, SEM1, LIT2, SEM2, WL1, GK1, GB1, WL2,
                                  GK2, GB2, x, xp);
  k_gru<<<64, 64, 0, stream>>>(xp, GRK1, GB1, GRK2, GB2, x);
  k_csr_count<<<32768, 128, 0, stream>>>(CFG1, CFG2, starts, counts, cursors);
  k_csr_alloc<<<128, 256, 0, stream>>>(starts, counts, fillpos, cursors);
  k_csr_fill<<<32768, 128, 0, stream>>>(CFG1, CFG2, starts, fillpos, edges);
  k_init<<<8192, 256, 0, stream>>>(x, wh);
  for (int step = 0; step < 3; ++step) {
    k_whg<<<1024, 64, 0, stream>>>(wh, WG, A1W, A1B, A2W, A2B, whg, ah1, ah2);
    k_attn<<<65536, 128, 0, stream>>>(wh, whg, ah1, ah2, starts, counts, edges);
  }
  k_mid<<<512, 256, 0, stream>>>(wh, mid);
  k_out<<<64, 64, 0, stream>>>(mid, WOUT, BOUT, e12);
  k_cos<<<1, 64, 0, stream>>>(e12, (float*)d_out);
}

// Round 2
// 1166.428 us; speedup vs baseline: 1.6357x; 1.6357x over previous
//
#include <hip/hip_runtime.h>

// Problem constants
#define BB 32
#define NNODE 512
#define EE 128
#define CAP 786432  // edge capacity per stream (expected ~419K)

__device__ __forceinline__ float sigm(float x) { return 1.0f / (1.0f + __expf(-x)); }
__device__ __forceinline__ float tanh_f(float x) {
  x = fminf(20.f, fmaxf(-20.f, x));
  float t = __expf(-2.f * x);
  return (1.f - t) / (1.f + t);
}

#define FMA4(ACC, OFF, RV, W)                                                  \
  ACC[(OFF) + 0] = fmaf((RV), (W).x, ACC[(OFF) + 0]);                          \
  ACC[(OFF) + 1] = fmaf((RV), (W).y, ACC[(OFF) + 1]);                          \
  ACC[(OFF) + 2] = fmaf((RV), (W).z, ACC[(OFF) + 2]);                          \
  ACC[(OFF) + 3] = fmaf((RV), (W).w, ACC[(OFF) + 3]);

// ---------------------------------------------------------------------------
// x[:, :, 0:64] = relu(LIT @ W_lit);  xp = SEM @ gru_k + gru_b[0]
// grid 1024 x 64.  bid>>1 = 64-row block, bid&1 = col half.
__global__ __launch_bounds__(64, 1) void k_data(
    const float* __restrict__ lit1, const float* __restrict__ sem1,
    const float* __restrict__ lit2, const float* __restrict__ sem2,
    const float* __restrict__ wl1, const float* __restrict__ gk1,
    const float* __restrict__ gb1, const float* __restrict__ wl2,
    const float* __restrict__ gk2, const float* __restrict__ gb2,
    float* __restrict__ x, float* __restrict__ xp) {
  __shared__ float stage[64 * 65];
  int bid = blockIdx.x;
  int rowblk = bid >> 1, half = bid & 1;
  int grow0 = rowblk * 64;
  int side = grow0 >> 14;
  int lrow0 = grow0 & 16383;
  const float* lit = side ? lit2 : lit1;
  const float* sem = side ? sem2 : sem1;
  const float* wl = side ? wl2 : wl1;
  const float* gk = side ? gk2 : gk1;
  const float* gb = side ? gb2 : gb1;
  int tid = threadIdx.x;
  int grow = grow0 + tid;

  // ---- literal matmul: 64 rows x 32 cols (this half) ----
  {
    const float4* lit4 = (const float4*)(lit + (size_t)lrow0 * 64);
#pragma unroll
    for (int p = 0; p < 16; ++p) {
      int s = p * 64 + tid;
      int r = s >> 4, q = s & 15;
      float4 v = lit4[r * 16 + q];
      stage[r * 65 + 4 * q + 0] = v.x;
      stage[r * 65 + 4 * q + 1] = v.y;
      stage[r * 65 + 4 * q + 2] = v.z;
      stage[r * 65 + 4 * q + 3] = v.w;
    }
    float acc[32];
#pragma unroll
    for (int c = 0; c < 32; ++c) acc[c] = 0.f;
    const float4* wl4 = (const float4*)wl;  // [64][16] f4
    for (int i = 0; i < 64; ++i) {
      float rv = stage[tid * 65 + i];
#pragma unroll
      for (int c4 = 0; c4 < 8; ++c4) {
        float4 w = wl4[i * 16 + half * 8 + c4];
        FMA4(acc, 4 * c4, rv, w)
      }
    }
    float4* x4 = (float4*)x;
#pragma unroll
    for (int c4 = 0; c4 < 8; ++c4) {
      float4 o;
      o.x = fmaxf(acc[4 * c4 + 0], 0.f);
      o.y = fmaxf(acc[4 * c4 + 1], 0.f);
      o.z = fmaxf(acc[4 * c4 + 2], 0.f);
      o.w = fmaxf(acc[4 * c4 + 3], 0.f);
      x4[(size_t)grow * 32 + half * 8 + c4] = o;
    }
  }
  // ---- semantic input projection: 64 rows x 96 cols (this half) ----
  {
    const float4* sem4 = (const float4*)(sem + (size_t)lrow0 * 64);
#pragma unroll
    for (int p = 0; p < 16; ++p) {
      int s = p * 64 + tid;
      int r = s >> 4, q = s & 15;
      float4 v = sem4[r * 16 + q];
      stage[r * 65 + 4 * q + 0] = v.x;
      stage[r * 65 + 4 * q + 1] = v.y;
      stage[r * 65 + 4 * q + 2] = v.z;
      stage[r * 65 + 4 * q + 3] = v.w;
    }
    float acc2[96];
#pragma unroll
    for (int c = 0; c < 96; ++c) acc2[c] = gb[half * 96 + c];  // bias row 0
    const float4* gk4 = (const float4*)gk;  // [64][48] f4
    for (int i = 0; i < 64; ++i) {
      float rv = stage[tid * 65 + i];
#pragma unroll
      for (int c4 = 0; c4 < 24; ++c4) {
        float4 w = gk4[i * 48 + half * 24 + c4];
        FMA4(acc2, 4 * c4, rv, w)
      }
    }
    float4* xp4 = (float4*)xp;
#pragma unroll
    for (int c4 = 0; c4 < 24; ++c4) {
      float4 o;
      o.x = acc2[4 * c4 + 0];
      o.y = acc2[4 * c4 + 1];
      o.z = acc2[4 * c4 + 2];
      o.w = acc2[4 * c4 + 3];
      xp4[(size_t)grow * 48 + half * 24 + c4] = o;
    }
  }
}

// ---------------------------------------------------------------------------
// GRU scan (Keras reset_after). One wave per (side,batch). 512 sequential steps.
// grid 64 x 64
__global__ __launch_bounds__(64, 1) void k_gru(
    const float* __restrict__ xp, const float* __restrict__ rk1,
    const float* __restrict__ b1, const float* __restrict__ rk2,
    const float* __restrict__ b2, float* __restrict__ x) {
  int blk = blockIdx.x;
  int side = blk >> 5, b = blk & 31;
  int j = threadIdx.x;
  const float* rk = side ? rk2 : rk1;
  const float* bb = side ? b2 : b1;
  float wz[64], wr[64], wv[64];
#pragma unroll
  for (int i = 0; i < 64; ++i) {
    wz[i] = rk[i * 192 + j];
    wr[i] = rk[i * 192 + 64 + j];
    wv[i] = rk[i * 192 + 128 + j];
  }
  float bz = bb[192 + j], brr = bb[192 + 64 + j], bv = bb[192 + 128 + j];
  __shared__ float hs[64];
  hs[j] = 0.f;
  float hj = 0.f;
  const float* xpr = xp + (size_t)(side * 16384 + b * 512) * 192;
  float* xrow = x + (size_t)(side * 16384 + b * 512) * 128;
  float cxz = xpr[j], cxr = xpr[64 + j], cxv = xpr[128 + j];
  for (int t = 0; t < 512; ++t) {
    float az = 0.f, ar = 0.f, av = 0.f;
    const float4* h4 = (const float4*)hs;
#pragma unroll
    for (int c = 0; c < 16; ++c) {
      float4 h = h4[c];
      az = fmaf(h.x, wz[4 * c + 0], az);
      az = fmaf(h.y, wz[4 * c + 1], az);
      az = fmaf(h.z, wz[4 * c + 2], az);
      az = fmaf(h.w, wz[4 * c + 3], az);
      ar = fmaf(h.x, wr[4 * c + 0], ar);
      ar = fmaf(h.y, wr[4 * c + 1], ar);
      ar = fmaf(h.z, wr[4 * c + 2], ar);
      ar = fmaf(h.w, wr[4 * c + 3], ar);
      av = fmaf(h.x, wv[4 * c + 0], av);
      av = fmaf(h.y, wv[4 * c + 1], av);
      av = fmaf(h.z, wv[4 * c + 2], av);
      av = fmaf(h.w, wv[4 * c + 3], av);
    }
    float nxz = 0.f, nxr = 0.f, nxv = 0.f;
    if (t + 1 < 512) {
      const float* p = xpr + (size_t)(t + 1) * 192;
      nxz = p[j];
      nxr = p[64 + j];
      nxv = p[128 + j];
    }
    float z = sigm(cxz + az + bz);
    float r = sigm(cxr + ar + brr);
    float hh = tanh_f(cxv + r * (av + bv));
    hj = fmaf(z, hj - hh, hh);  // z*h + (1-z)*hh
    xrow[(size_t)t * 128 + 64 + j] = hj;
    hs[j] = hj;  // single wave: LDS ops in program order, no barrier needed
    cxz = nxz;
    cxr = nxr;
    cxv = nxv;
  }
}

// ---------------------------------------------------------------------------
// CSR/CSC build, pass 1: counts.  grid 512 x 256.
// Block = (side s, batch b, chunk ch of 64 rows). All counting in LDS.
__global__ __launch_bounds__(256, 1) void k_count(
    const float* __restrict__ A1, const float* __restrict__ A2,
    int* __restrict__ counts, int* __restrict__ ccolchunk) {
  int bid = blockIdx.x;
  int s = bid >> 8, b = (bid >> 3) & 31, ch = bid & 7;
  const float* A = s ? A2 : A1;
  const float4* A4 = (const float4*)(A + ((size_t)b * 512 + ch * 64) * 512);
  int t = threadIdx.x;
  __shared__ int ccol[512];
  __shared__ int crow[64];
  ccol[t] = 0;
  ccol[t + 256] = 0;
  if (t < 64) crow[t] = 0;
  __syncthreads();
#pragma unroll
  for (int it = 0; it < 32; ++it) {
    int idx = it * 256 + t;
    int r = idx >> 7, c4 = idx & 127;
    float4 v = A4[idx];
    int n = 0;
    if (v.x != 0.f) { atomicAdd(&ccol[4 * c4 + 0], 1); n++; }
    if (v.y != 0.f) { atomicAdd(&ccol[4 * c4 + 1], 1); n++; }
    if (v.z != 0.f) { atomicAdd(&ccol[4 * c4 + 2], 1); n++; }
    if (v.w != 0.f) { atomicAdd(&ccol[4 * c4 + 3], 1); n++; }
    if (n) atomicAdd(&crow[r], n);
  }
  __syncthreads();
  if (t < 64) counts[(2 * s) * 16384 + b * 512 + ch * 64 + t] = crow[t];
  int cbase = ((s * 32 + b) * 8 + ch) * 512;
  ccolchunk[cbase + t] = ccol[t];
  ccolchunk[cbase + t + 256] = ccol[t + 256];
}

// ---------------------------------------------------------------------------
// CSR/CSC build, pass 2: offsets. grid 256 x 256.
// bid<128: fwd rows; bid>=128: rev cols (+ per-chunk bases).
__global__ __launch_bounds__(256, 1) void k_alloc(
    const int* __restrict__ ccolchunk, int* __restrict__ counts,
    int* __restrict__ starts, int* __restrict__ chunkbase,
    int* __restrict__ cursors) {
  int bid = blockIdx.x;
  int t = threadIdx.x;
  int lane = t & 63, wave = t >> 6;
  __shared__ int wsum[4];
  __shared__ int gbase;

  int c, cursor_idx, out_idx;
  int pchunk[8];
  if (bid < 128) {
    int fr = bid * 256 + t;  // 0..32767
    int s = fr >> 14;
    out_idx = (2 * s) * 16384 + (fr & 16383);
    cursor_idx = 2 * s;
    c = counts[out_idx];
  } else {
    int cid = (bid - 128) * 256 + t;  // 0..32767 -> (s,b,j)
    int s = cid >> 14, b = (cid >> 9) & 31, j = cid & 511;
    out_idx = (2 * s + 1) * 16384 + b * 512 + j;
    cursor_idx = 2 * s + 1;
    c = 0;
#pragma unroll
    for (int ch = 0; ch < 8; ++ch) {
      pchunk[ch] = ccolchunk[((s * 32 + b) * 8 + ch) * 512 + j];
      c += pchunk[ch];
    }
    counts[out_idx] = c;
  }
  // block exclusive scan
  int v = c;
#pragma unroll
  for (int d = 1; d < 64; d <<= 1) {
    int o = __shfl_up(v, d, 64);
    if (lane >= d) v += o;
  }
  if (lane == 63) wsum[wave] = v;
  __syncthreads();
  int wbase = 0;
  for (int w = 0; w < wave; ++w) wbase += w < 4 ? wsum[w] : 0;
  int tot = wsum[0] + wsum[1] + wsum[2] + wsum[3];
  if (t == 0) gbase = atomicAdd(&cursors[cursor_idx], tot);
  __syncthreads();
  int start = gbase + wbase + v - c;
  starts[out_idx] = start;
  if (bid >= 128) {
    int cid = (bid - 128) * 256 + t;
    int s = cid >> 14, b = (cid >> 9) & 31, j = cid & 511;
    int run = start;
#pragma unroll
    for (int ch = 0; ch < 8; ++ch) {
      chunkbase[((s * 32 + b) * 8 + ch) * 512 + j] = run;
      run += pchunk[ch];
    }
  }
}

// ---------------------------------------------------------------------------
// CSR/CSC build, pass 3: fill. grid 512 x 256. LDS-atomic positions only.
__global__ __launch_bounds__(256, 1) void k_fill(
    const float* __restrict__ A1, const float* __restrict__ A2,
    const int* __restrict__ starts, const int* __restrict__ chunkbase,
    int* __restrict__ edges) {
  int bid = blockIdx.x;
  int s = bid >> 8, b = (bid >> 3) & 31, ch = bid & 7;
  const float* A = s ? A2 : A1;
  const float4* A4 = (const float4*)(A + ((size_t)b * 512 + ch * 64) * 512);
  int t = threadIdx.x;
  __shared__ int ccol[512];  // local position within (chunk, col)
  __shared__ int cb[512];    // chunkbase for this block
  __shared__ int crow[64];
  __shared__ int sf[64];
  ccol[t] = 0;
  ccol[t + 256] = 0;
  int cbase = ((s * 32 + b) * 8 + ch) * 512;
  cb[t] = chunkbase[cbase + t];
  cb[t + 256] = chunkbase[cbase + t + 256];
  if (t < 64) {
    crow[t] = 0;
    sf[t] = starts[(2 * s) * 16384 + b * 512 + ch * 64 + t];
  }
  __syncthreads();
  int* efwd = edges + (size_t)(2 * s) * CAP;
  int* erev = edges + (size_t)(2 * s + 1) * CAP;
#pragma unroll
  for (int it = 0; it < 32; ++it) {
    int idx = it * 256 + t;
    int r = idx >> 7, c4 = idx & 127;
    float4 v = A4[idx];
    float vv[4] = {v.x, v.y, v.z, v.w};
    int i = ch * 64 + r;
#pragma unroll
    for (int e = 0; e < 4; ++e) {
      if (vv[e] != 0.f) {
        int j = 4 * c4 + e;
        int lp = atomicAdd(&ccol[j], 1);
        int ri = cb[j] + lp;
        if (ri < CAP) erev[ri] = i;
        int fp = atomicAdd(&crow[r], 1);
        int fi = sf[r] + fp;
        if (fi < CAP) efwd[fi] = j;
      }
    }
  }
}

// ---------------------------------------------------------------------------
// wh[st] = relu(x[side(st)]). grid 8192 x 256 over f4.
__global__ void k_init(const float* __restrict__ x, float* __restrict__ wh) {
  int idx = blockIdx.x * 256 + threadIdx.x;
  int st = idx >> 19;  // 524288 f4 per stream
  int loc = idx & 524287;
  int side = st >> 1;
  float4 v = ((const float4*)x)[(size_t)side * 524288 + loc];
  v.x = fmaxf(v.x, 0.f);
  v.y = fmaxf(v.y, 0.f);
  v.z = fmaxf(v.z, 0.f);
  v.w = fmaxf(v.w, 0.f);
  ((float4*)wh)[idx] = v;
}

// ---------------------------------------------------------------------------
// whg = wh @ W_g;  ah1 = wh@a1_w + a1_b;  ah2 = wh@a2_w + a2_b
// grid 1024 x 64; one wave = 64 rows, acc[128] in regs, W_g via uniform loads.
__global__ __launch_bounds__(64, 1) void k_whg(
    const float* __restrict__ wh, const float* __restrict__ Wg,
    const float* __restrict__ a1w, const float* __restrict__ a1b,
    const float* __restrict__ a2w, const float* __restrict__ a2b,
    float* __restrict__ whg, float* __restrict__ ah1, float* __restrict__ ah2) {
  __shared__ float stage[64 * 129];
  int rowbase = blockIdx.x * 64;
  int tid = threadIdx.x;
  const float4* wh4 = (const float4*)(wh + (size_t)rowbase * 128);
#pragma unroll
  for (int p = 0; p < 32; ++p) {
    int s = p * 64 + tid;
    int r = s >> 5, q = s & 31;
    float4 v = wh4[r * 32 + q];
    stage[r * 129 + 4 * q + 0] = v.x;
    stage[r * 129 + 4 * q + 1] = v.y;
    stage[r * 129 + 4 * q + 2] = v.z;
    stage[r * 129 + 4 * q + 3] = v.w;
  }
  float acc[128];
#pragma unroll
  for (int c = 0; c < 128; ++c) acc[c] = 0.f;
  float p1 = a1b[0], p2 = a2b[0];
  const float4* Wg4 = (const float4*)Wg;  // [128][32] f4
  for (int i = 0; i < 128; ++i) {
    float rv = stage[tid * 129 + i];
    p1 = fmaf(rv, a1w[i], p1);
    p2 = fmaf(rv, a2w[i], p2);
#pragma unroll
    for (int c4 = 0; c4 < 32; ++c4) {
      float4 w = Wg4[i * 32 + c4];
      FMA4(acc, 4 * c4, rv, w)
    }
  }
  int grow = rowbase + tid;
  float4* o4 = (float4*)(whg + (size_t)grow * 128);
#pragma unroll
  for (int c4 = 0; c4 < 32; ++c4) {
    float4 o;
    o.x = acc[4 * c4 + 0];
    o.y = acc[4 * c4 + 1];
    o.z = acc[4 * c4 + 2];
    o.w = acc[4 * c4 + 3];
    o4[c4] = o;
  }
  ah1[grow] = p1;
  ah2[grow] = p2;
}

// ---------------------------------------------------------------------------
// Per-row edge softmax + aggregate + elu update. grid 65536 x 128.
__global__ __launch_bounds__(128, 1) void k_attn(
    float* __restrict__ wh, const float* __restrict__ whg,
    const float* __restrict__ ah1, const float* __restrict__ ah2,
    const int* __restrict__ starts, const int* __restrict__ counts,
    const int* __restrict__ edges) {
  int row = blockIdx.x;
  int st = row >> 14;
  int base = row & ~511;  // row index of (st,b) block start
  int t = threadIdx.x;
  __shared__ int jl[512];
  __shared__ float el[512];
  __shared__ float red[2];
  int start = starts[row], cnt = counts[row];
  const int* ed = edges + (size_t)st * CAP + start;
  float a1v = ah1[row];
  const float* ah2b = ah2 + base;
  float lmax = -1e30f;
  for (int k = t; k < cnt; k += 128) {
    int jj = ed[k];
    float e = a1v + ah2b[jj];
    e = e >= 0.f ? e : 0.2f * e;  // leaky_relu 0.2
    jl[k] = jj;
    el[k] = e;
    lmax = fmaxf(lmax, e);
  }
  for (int off = 32; off; off >>= 1) lmax = fmaxf(lmax, __shfl_xor(lmax, off, 64));
  if ((t & 63) == 0) red[t >> 6] = lmax;
  __syncthreads();
  float m = fmaxf(red[0], red[1]);
  __syncthreads();
  float lsum = 0.f;
  for (int k = t; k < cnt; k += 128) {
    float w = __expf(el[k] - m);
    el[k] = w;
    lsum += w;
  }
  for (int off = 32; off; off >>= 1) lsum += __shfl_xor(lsum, off, 64);
  if ((t & 63) == 0) red[t >> 6] = lsum;
  __syncthreads();
  float Z = red[0] + red[1];
  float inv = cnt > 0 ? 1.0f / Z : 0.f;
  float acc = 0.f;
  const float* wgb = whg + (size_t)base * 128;
  for (int k = 0; k < cnt; ++k) {
    acc = fmaf(el[k], wgb[(size_t)jl[k] * 128 + t], acc);
  }
  acc *= inv;
  float v = wh[(size_t)row * 128 + t] + acc;
  wh[(size_t)row * 128 + t] = v > 0.f ? v : __expf(v) - 1.f;  // elu
}

// ---------------------------------------------------------------------------
// mid[side][b][c] = sum_i (wh[2s][b][i][c] + wh[2s+1][b][i][c]). grid 512x256.
__global__ void k_mid(const float* __restrict__ wh, float* __restrict__ mid) {
  int blk = blockIdx.x;
  int side = blk >> 8, b = (blk >> 3) & 31, ch = blk & 7;
  int t = threadIdx.x;
  int c = t & 127, hh = t >> 7;
  float sum = 0.f;
  size_t b0 = ((size_t)(2 * side) * 16384 + b * 512) * 128;
  size_t b1 = ((size_t)(2 * side + 1) * 16384 + b * 512) * 128;
  for (int q = 0; q < 32; ++q) {
    int i = ch * 64 + hh * 32 + q;
    sum += wh[b0 + (size_t)i * 128 + c];
    sum += wh[b1 + (size_t)i * 128 + c];
  }
  atomicAdd(&mid[(side * 32 + b) * 128 + c], sum);
}

__global__ void k_out(const float* __restrict__ mid,
                      const float* __restrict__ Wout,
                      const float* __restrict__ bout, float* __restrict__ e12) {
  int sb = blockIdx.x;  // 0..63  (side*32+b)
  int o = threadIdx.x;  // 0..63
  const float* m = mid + sb * 128;
  float acc = bout[o];
  for (int k = 0; k < 128; ++k) acc = fmaf(m[k], Wout[k * 64 + o], acc);
  e12[sb * 64 + o] = acc;
}

__global__ void k_cos(const float* __restrict__ e12, float* __restrict__ out) {
  int b = threadIdx.x;
  if (b >= 32) return;
  const float* e1 = e12 + b * 64;
  const float* e2 = e12 + 2048 + b * 64;
  float d = 0.f, n1 = 0.f, n2 = 0.f;
  for (int o = 0; o < 64; ++o) {
    float a = e1[o], c = e2[o];
    d = fmaf(a, c, d);
    n1 = fmaf(a, a, n1);
    n2 = fmaf(c, c, n2);
  }
  float nn = fmaxf(sqrtf(n1), 1e-12f) * fmaxf(sqrtf(n2), 1e-12f);
  out[b] = 0.5f * (1.f + d / nn);
}

// ---------------------------------------------------------------------------
extern "C" void kernel_launch(void* const* d_in, const int* in_sizes, int n_in,
                              void* d_out, int out_size, void* d_ws,
                              size_t ws_size, hipStream_t stream) {
  const float* CFG1 = (const float*)d_in[0];
  const float* LIT1 = (const float*)d_in[2];
  const float* SEM1 = (const float*)d_in[3];
  const float* CFG2 = (const float*)d_in[4];
  const float* LIT2 = (const float*)d_in[6];
  const float* SEM2 = (const float*)d_in[7];
  const float* WL1 = (const float*)d_in[8];
  const float* GK1 = (const float*)d_in[9];
  const float* GRK1 = (const float*)d_in[10];
  const float* GB1 = (const float*)d_in[11];
  const float* WL2 = (const float*)d_in[12];
  const float* GK2 = (const float*)d_in[13];
  const float* GRK2 = (const float*)d_in[14];
  const float* GB2 = (const float*)d_in[15];
  const float* A1W = (const float*)d_in[16];
  const float* A1B = (const float*)d_in[17];
  const float* A2W = (const float*)d_in[18];
  const float* A2B = (const float*)d_in[19];
  const float* WG = (const float*)d_in[20];
  const float* WOUT = (const float*)d_in[21];
  const float* BOUT = (const float*)d_in[22];

  float* ws = (float*)d_ws;
  float* wh = ws;             // 8388608
  float* whg = wh + 8388608;  // 8388608 (xp aliases; tail aliases csr scratch)
  float* xp = whg;            // [2][16384][192] = 6291456 < 8388608
  // csr scratch in whg tail (free during xp phase, dead before k_whg)
  int* ccolchunk = (int*)(whg + 6291456);  // 262144
  int* chunkbase = ccolchunk + 262144;     // 262144
  float* x = whg + 8388608;                // 4194304
  float* ah1 = x + 4194304;                // 65536
  float* ah2 = ah1 + 65536;                // 65536
  float* mid = ah2 + 65536;                // 8192
  float* e12 = mid + 8192;                 // 4096
  int* starts = (int*)(e12 + 4096);        // 65536
  int* counts = starts + 65536;            // 65536
  int* cursors = counts + 65536;           // 64
  int* edges = cursors + 64;               // 4*CAP

  hipMemsetAsync(cursors, 0, 64 * 4, stream);
  hipMemsetAsync(mid, 0, 8192 * 4, stream);

  k_data<<<1024, 64, 0, stream>>>(LIT1, SEM1, LIT2, SEM2, WL1, GK1, GB1, WL2,
                                  GK2, GB2, x, xp);
  k_gru<<<64, 64, 0, stream>>>(xp, GRK1, GB1, GRK2, GB2, x);
  k_count<<<512, 256, 0, stream>>>(CFG1, CFG2, counts, ccolchunk);
  k_alloc<<<256, 256, 0, stream>>>(ccolchunk, counts, starts, chunkbase,
                                   cursors);
  k_fill<<<512, 256, 0, stream>>>(CFG1, CFG2, starts, chunkbase, edges);
  k_init<<<8192, 256, 0, stream>>>(x, wh);
  for (int step = 0; step < 3; ++step) {
    k_whg<<<1024, 64, 0, stream>>>(wh, WG, A1W, A1B, A2W, A2B, whg, ah1, ah2);
    k_attn<<<65536, 128, 0, stream>>>(wh, whg, ah1, ah2, starts, counts, edges);
  }
  k_mid<<<512, 256, 0, stream>>>(wh, mid);
  k_out<<<64, 64, 0, stream>>>(mid, WOUT, BOUT, e12);
  k_cos<<<1, 64, 0, stream>>>(e12, (float*)d_out);
}

// Round 3
// 1094.010 us; speedup vs baseline: 1.7440x; 1.0662x over previous
//
#include <hip/hip_runtime.h>

// Problem constants
#define BB 32
#define NNODE 512
#define EE 128
#define CAP 786432  // edge capacity per stream (expected ~419K)

typedef float v2f __attribute__((ext_vector_type(2)));
__device__ __forceinline__ v2f fma2(v2f a, v2f b, v2f c) {
  return __builtin_elementwise_fma(a, b, c);
}

__device__ __forceinline__ float sigm(float x) { return 1.0f / (1.0f + __expf(-x)); }
__device__ __forceinline__ float tanh_f(float x) {
  x = fminf(20.f, fmaxf(-20.f, x));
  float t = __expf(-2.f * x);
  return (1.f - t) / (1.f + t);
}

// ---------------------------------------------------------------------------
// x[:, :, 0:64] = relu(LIT @ W_lit);  xp = SEM @ gru_k + gru_b[0]
// grid 1024 x 64.  bid>>1 = 64-row block, bid&1 = col half.
__global__ __launch_bounds__(64, 1) void k_data(
    const float* __restrict__ lit1, const float* __restrict__ sem1,
    const float* __restrict__ lit2, const float* __restrict__ sem2,
    const float* __restrict__ wl1, const float* __restrict__ gk1,
    const float* __restrict__ gb1, const float* __restrict__ wl2,
    const float* __restrict__ gk2, const float* __restrict__ gb2,
    float* __restrict__ x, float* __restrict__ xp) {
  __shared__ float stage[64 * 65];
  int bid = blockIdx.x;
  int rowblk = bid >> 1, half = bid & 1;
  int grow0 = rowblk * 64;
  int side = grow0 >> 14;
  int lrow0 = grow0 & 16383;
  const float* lit = side ? lit2 : lit1;
  const float* sem = side ? sem2 : sem1;
  const float* wl = side ? wl2 : wl1;
  const float* gk = side ? gk2 : gk1;
  const float* gb = side ? gb2 : gb1;
  int tid = threadIdx.x;
  int grow = grow0 + tid;

  // ---- literal matmul: 64 rows x 32 cols (this half) ----
  {
    const float4* lit4 = (const float4*)(lit + (size_t)lrow0 * 64);
#pragma unroll
    for (int p = 0; p < 16; ++p) {
      int s = p * 64 + tid;
      int r = s >> 4, q = s & 15;
      float4 v = lit4[r * 16 + q];
      stage[r * 65 + 4 * q + 0] = v.x;
      stage[r * 65 + 4 * q + 1] = v.y;
      stage[r * 65 + 4 * q + 2] = v.z;
      stage[r * 65 + 4 * q + 3] = v.w;
    }
    v2f acc[16];
#pragma unroll
    for (int c = 0; c < 16; ++c) acc[c] = (v2f){0.f, 0.f};
    const float4* wl4 = (const float4*)wl;  // [64][16] f4
    for (int i = 0; i < 64; ++i) {
      float rv = stage[tid * 65 + i];
      v2f rv2 = {rv, rv};
#pragma unroll
      for (int c4 = 0; c4 < 8; ++c4) {
        float4 w = wl4[i * 16 + half * 8 + c4];
        acc[2 * c4 + 0] = fma2(rv2, (v2f){w.x, w.y}, acc[2 * c4 + 0]);
        acc[2 * c4 + 1] = fma2(rv2, (v2f){w.z, w.w}, acc[2 * c4 + 1]);
      }
    }
    float4* x4 = (float4*)x;
#pragma unroll
    for (int c4 = 0; c4 < 8; ++c4) {
      float4 o;
      o.x = fmaxf(acc[2 * c4].x, 0.f);
      o.y = fmaxf(acc[2 * c4].y, 0.f);
      o.z = fmaxf(acc[2 * c4 + 1].x, 0.f);
      o.w = fmaxf(acc[2 * c4 + 1].y, 0.f);
      x4[(size_t)grow * 32 + half * 8 + c4] = o;
    }
  }
  // ---- semantic input projection: 64 rows x 96 cols (this half) ----
  {
    const float4* sem4 = (const float4*)(sem + (size_t)lrow0 * 64);
#pragma unroll
    for (int p = 0; p < 16; ++p) {
      int s = p * 64 + tid;
      int r = s >> 4, q = s & 15;
      float4 v = sem4[r * 16 + q];
      stage[r * 65 + 4 * q + 0] = v.x;
      stage[r * 65 + 4 * q + 1] = v.y;
      stage[r * 65 + 4 * q + 2] = v.z;
      stage[r * 65 + 4 * q + 3] = v.w;
    }
    v2f acc2[48];
#pragma unroll
    for (int c = 0; c < 48; ++c)
      acc2[c] = (v2f){gb[half * 96 + 2 * c], gb[half * 96 + 2 * c + 1]};
    const float4* gk4 = (const float4*)gk;  // [64][48] f4
    for (int i = 0; i < 64; ++i) {
      float rv = stage[tid * 65 + i];
      v2f rv2 = {rv, rv};
#pragma unroll
      for (int c4 = 0; c4 < 24; ++c4) {
        float4 w = gk4[i * 48 + half * 24 + c4];
        acc2[2 * c4 + 0] = fma2(rv2, (v2f){w.x, w.y}, acc2[2 * c4 + 0]);
        acc2[2 * c4 + 1] = fma2(rv2, (v2f){w.z, w.w}, acc2[2 * c4 + 1]);
      }
    }
    float4* xp4 = (float4*)xp;
#pragma unroll
    for (int c4 = 0; c4 < 24; ++c4) {
      float4 o;
      o.x = acc2[2 * c4].x;
      o.y = acc2[2 * c4].y;
      o.z = acc2[2 * c4 + 1].x;
      o.w = acc2[2 * c4 + 1].y;
      xp4[(size_t)grow * 48 + half * 24 + c4] = o;
    }
  }
}

// ---------------------------------------------------------------------------
// GRU scan (Keras reset_after). One wave per (side,batch). 512 sequential steps.
// Packed-f32 FMAs, 2 chains/gate. grid 64 x 64.
__global__ __launch_bounds__(64, 1) void k_gru(
    const float* __restrict__ xp, const float* __restrict__ rk1,
    const float* __restrict__ b1, const float* __restrict__ rk2,
    const float* __restrict__ b2, float* __restrict__ x) {
  int blk = blockIdx.x;
  int side = blk >> 5, b = blk & 31;
  int j = threadIdx.x;
  const float* rk = side ? rk2 : rk1;
  const float* bb = side ? b2 : b1;
  v2f wz[32], wr[32], wv[32];
#pragma unroll
  for (int i = 0; i < 32; ++i) {
    wz[i] = (v2f){rk[(2 * i) * 192 + j], rk[(2 * i + 1) * 192 + j]};
    wr[i] = (v2f){rk[(2 * i) * 192 + 64 + j], rk[(2 * i + 1) * 192 + 64 + j]};
    wv[i] = (v2f){rk[(2 * i) * 192 + 128 + j], rk[(2 * i + 1) * 192 + 128 + j]};
  }
  float bz = bb[192 + j], brr = bb[192 + 64 + j], bv = bb[192 + 128 + j];
  __shared__ float hs[64];
  hs[j] = 0.f;
  float hj = 0.f;
  const float* xpr = xp + (size_t)(side * 16384 + b * 512) * 192;
  float* xrow = x + (size_t)(side * 16384 + b * 512) * 128;
  float cxz = xpr[j], cxr = xpr[64 + j], cxv = xpr[128 + j];
  for (int t = 0; t < 512; ++t) {
    v2f az0 = {0.f, 0.f}, az1 = {0.f, 0.f};
    v2f ar0 = {0.f, 0.f}, ar1 = {0.f, 0.f};
    v2f av0 = {0.f, 0.f}, av1 = {0.f, 0.f};
    const float4* h4p = (const float4*)hs;
#pragma unroll
    for (int c = 0; c < 16; ++c) {
      float4 h = h4p[c];
      v2f hlo = {h.x, h.y}, hhi = {h.z, h.w};
      az0 = fma2(hlo, wz[2 * c], az0);
      az1 = fma2(hhi, wz[2 * c + 1], az1);
      ar0 = fma2(hlo, wr[2 * c], ar0);
      ar1 = fma2(hhi, wr[2 * c + 1], ar1);
      av0 = fma2(hlo, wv[2 * c], av0);
      av1 = fma2(hhi, wv[2 * c + 1], av1);
    }
    float nxz = 0.f, nxr = 0.f, nxv = 0.f;
    if (t + 1 < 512) {
      const float* p = xpr + (size_t)(t + 1) * 192;
      nxz = p[j];
      nxr = p[64 + j];
      nxv = p[128 + j];
    }
    az0 += az1;
    ar0 += ar1;
    av0 += av1;
    float az = az0.x + az0.y, ar = ar0.x + ar0.y, av = av0.x + av0.y;
    float z = sigm(cxz + az + bz);
    float r = sigm(cxr + ar + brr);
    float hh = tanh_f(cxv + r * (av + bv));
    hj = fmaf(z, hj - hh, hh);  // z*h + (1-z)*hh
    xrow[(size_t)t * 128 + 64 + j] = hj;
    hs[j] = hj;  // single wave: LDS ops in program order, no barrier needed
    cxz = nxz;
    cxr = nxr;
    cxv = nxv;
  }
}

// ---------------------------------------------------------------------------
// CSR/CSC build, pass 1: counts.  grid 512 x 256.
// Block = (side s, batch b, chunk ch of 64 rows). All counting in LDS.
__global__ __launch_bounds__(256, 1) void k_count(
    const float* __restrict__ A1, const float* __restrict__ A2,
    int* __restrict__ counts, int* __restrict__ ccolchunk) {
  int bid = blockIdx.x;
  int s = bid >> 8, b = (bid >> 3) & 31, ch = bid & 7;
  const float* A = s ? A2 : A1;
  const float4* A4 = (const float4*)(A + ((size_t)b * 512 + ch * 64) * 512);
  int t = threadIdx.x;
  __shared__ int ccol[512];
  __shared__ int crow[64];
  ccol[t] = 0;
  ccol[t + 256] = 0;
  if (t < 64) crow[t] = 0;
  __syncthreads();
#pragma unroll
  for (int it = 0; it < 32; ++it) {
    int idx = it * 256 + t;
    int r = idx >> 7, c4 = idx & 127;
    float4 v = A4[idx];
    int n = 0;
    if (v.x != 0.f) { atomicAdd(&ccol[4 * c4 + 0], 1); n++; }
    if (v.y != 0.f) { atomicAdd(&ccol[4 * c4 + 1], 1); n++; }
    if (v.z != 0.f) { atomicAdd(&ccol[4 * c4 + 2], 1); n++; }
    if (v.w != 0.f) { atomicAdd(&ccol[4 * c4 + 3], 1); n++; }
    if (n) atomicAdd(&crow[r], n);
  }
  __syncthreads();
  if (t < 64) counts[(2 * s) * 16384 + b * 512 + ch * 64 + t] = crow[t];
  int cbase = ((s * 32 + b) * 8 + ch) * 512;
  ccolchunk[cbase + t] = ccol[t];
  ccolchunk[cbase + t + 256] = ccol[t + 256];
}

// ---------------------------------------------------------------------------
// CSR/CSC build, pass 2: offsets. grid 256 x 256.
// bid<128: fwd rows; bid>=128: rev cols (+ per-chunk bases).
__global__ __launch_bounds__(256, 1) void k_alloc(
    const int* __restrict__ ccolchunk, int* __restrict__ counts,
    int* __restrict__ starts, int* __restrict__ chunkbase,
    int* __restrict__ cursors) {
  int bid = blockIdx.x;
  int t = threadIdx.x;
  int lane = t & 63, wave = t >> 6;
  __shared__ int wsum[4];
  __shared__ int gbase;

  int c, cursor_idx, out_idx;
  int pchunk[8];
  if (bid < 128) {
    int fr = bid * 256 + t;  // 0..32767
    int s = fr >> 14;
    out_idx = (2 * s) * 16384 + (fr & 16383);
    cursor_idx = 2 * s;
    c = counts[out_idx];
  } else {
    int cid = (bid - 128) * 256 + t;  // 0..32767 -> (s,b,j)
    int s = cid >> 14, b = (cid >> 9) & 31, j = cid & 511;
    out_idx = (2 * s + 1) * 16384 + b * 512 + j;
    cursor_idx = 2 * s + 1;
    c = 0;
#pragma unroll
    for (int ch = 0; ch < 8; ++ch) {
      pchunk[ch] = ccolchunk[((s * 32 + b) * 8 + ch) * 512 + j];
      c += pchunk[ch];
    }
    counts[out_idx] = c;
  }
  // block exclusive scan
  int v = c;
#pragma unroll
  for (int d = 1; d < 64; d <<= 1) {
    int o = __shfl_up(v, d, 64);
    if (lane >= d) v += o;
  }
  if (lane == 63) wsum[wave] = v;
  __syncthreads();
  int wbase = 0;
  for (int w = 0; w < wave; ++w) wbase += w < 4 ? wsum[w] : 0;
  int tot = wsum[0] + wsum[1] + wsum[2] + wsum[3];
  if (t == 0) gbase = atomicAdd(&cursors[cursor_idx], tot);
  __syncthreads();
  int start = gbase + wbase + v - c;
  starts[out_idx] = start;
  if (bid >= 128) {
    int cid = (bid - 128) * 256 + t;
    int s = cid >> 14, b = (cid >> 9) & 31, j = cid & 511;
    int run = start;
#pragma unroll
    for (int ch = 0; ch < 8; ++ch) {
      chunkbase[((s * 32 + b) * 8 + ch) * 512 + j] = run;
      run += pchunk[ch];
    }
  }
}

// ---------------------------------------------------------------------------
// CSR/CSC build, pass 3: fill. grid 512 x 256. LDS-atomic positions only.
__global__ __launch_bounds__(256, 1) void k_fill(
    const float* __restrict__ A1, const float* __restrict__ A2,
    const int* __restrict__ starts, const int* __restrict__ chunkbase,
    int* __restrict__ edges) {
  int bid = blockIdx.x;
  int s = bid >> 8, b = (bid >> 3) & 31, ch = bid & 7;
  const float* A = s ? A2 : A1;
  const float4* A4 = (const float4*)(A + ((size_t)b * 512 + ch * 64) * 512);
  int t = threadIdx.x;
  __shared__ int ccol[512];  // local position within (chunk, col)
  __shared__ int cb[512];    // chunkbase for this block
  __shared__ int crow[64];
  __shared__ int sf[64];
  ccol[t] = 0;
  ccol[t + 256] = 0;
  int cbase = ((s * 32 + b) * 8 + ch) * 512;
  cb[t] = chunkbase[cbase + t];
  cb[t + 256] = chunkbase[cbase + t + 256];
  if (t < 64) {
    crow[t] = 0;
    sf[t] = starts[(2 * s) * 16384 + b * 512 + ch * 64 + t];
  }
  __syncthreads();
  int* efwd = edges + (size_t)(2 * s) * CAP;
  int* erev = edges + (size_t)(2 * s + 1) * CAP;
#pragma unroll
  for (int it = 0; it < 32; ++it) {
    int idx = it * 256 + t;
    int r = idx >> 7, c4 = idx & 127;
    float4 v = A4[idx];
    float vv[4] = {v.x, v.y, v.z, v.w};
    int i = ch * 64 + r;
#pragma unroll
    for (int e = 0; e < 4; ++e) {
      if (vv[e] != 0.f) {
        int j = 4 * c4 + e;
        int lp = atomicAdd(&ccol[j], 1);
        int ri = cb[j] + lp;
        if (ri < CAP) erev[ri] = i;
        int fp = atomicAdd(&crow[r], 1);
        int fi = sf[r] + fp;
        if (fi < CAP) efwd[fi] = j;
      }
    }
  }
}

// ---------------------------------------------------------------------------
// wh[st] = relu(x[side(st)]). grid 8192 x 256 over f4.
__global__ void k_init(const float* __restrict__ x, float* __restrict__ wh) {
  int idx = blockIdx.x * 256 + threadIdx.x;
  int st = idx >> 19;  // 524288 f4 per stream
  int loc = idx & 524287;
  int side = st >> 1;
  float4 v = ((const float4*)x)[(size_t)side * 524288 + loc];
  v.x = fmaxf(v.x, 0.f);
  v.y = fmaxf(v.y, 0.f);
  v.z = fmaxf(v.z, 0.f);
  v.w = fmaxf(v.w, 0.f);
  ((float4*)wh)[idx] = v;
}

// ---------------------------------------------------------------------------
// whg = wh @ W_g;  ah1 = wh@a1_w + a1_b;  ah2 = wh@a2_w + a2_b
// grid 1024 x 64; one wave = 64 rows, packed-f32 acc, W_g via uniform loads.
__global__ __launch_bounds__(64, 1) void k_whg(
    const float* __restrict__ wh, const float* __restrict__ Wg,
    const float* __restrict__ a1w, const float* __restrict__ a1b,
    const float* __restrict__ a2w, const float* __restrict__ a2b,
    float* __restrict__ whg, float* __restrict__ ah1, float* __restrict__ ah2) {
  __shared__ float stage[64 * 129];
  int rowbase = blockIdx.x * 64;
  int tid = threadIdx.x;
  const float4* wh4 = (const float4*)(wh + (size_t)rowbase * 128);
#pragma unroll
  for (int p = 0; p < 32; ++p) {
    int s = p * 64 + tid;
    int r = s >> 5, q = s & 31;
    float4 v = wh4[r * 32 + q];
    stage[r * 129 + 4 * q + 0] = v.x;
    stage[r * 129 + 4 * q + 1] = v.y;
    stage[r * 129 + 4 * q + 2] = v.z;
    stage[r * 129 + 4 * q + 3] = v.w;
  }
  v2f acc[64];
#pragma unroll
  for (int c = 0; c < 64; ++c) acc[c] = (v2f){0.f, 0.f};
  float p1 = a1b[0], p2 = a2b[0];
  const float4* Wg4 = (const float4*)Wg;  // [128][32] f4
  for (int i = 0; i < 128; ++i) {
    float rv = stage[tid * 129 + i];
    v2f rv2 = {rv, rv};
    p1 = fmaf(rv, a1w[i], p1);
    p2 = fmaf(rv, a2w[i], p2);
#pragma unroll
    for (int c4 = 0; c4 < 32; ++c4) {
      float4 w = Wg4[i * 32 + c4];
      acc[2 * c4 + 0] = fma2(rv2, (v2f){w.x, w.y}, acc[2 * c4 + 0]);
      acc[2 * c4 + 1] = fma2(rv2, (v2f){w.z, w.w}, acc[2 * c4 + 1]);
    }
  }
  int grow = rowbase + tid;
  float4* o4 = (float4*)(whg + (size_t)grow * 128);
#pragma unroll
  for (int c4 = 0; c4 < 32; ++c4) {
    float4 o;
    o.x = acc[2 * c4].x;
    o.y = acc[2 * c4].y;
    o.z = acc[2 * c4 + 1].x;
    o.w = acc[2 * c4 + 1].y;
    o4[c4] = o;
  }
  ah1[grow] = p1;
  ah2[grow] = p2;
}

// ---------------------------------------------------------------------------
// Per-row edge softmax + aggregate + elu update. grid 65536 x 128.
__global__ __launch_bounds__(128, 1) void k_attn(
    float* __restrict__ wh, const float* __restrict__ whg,
    const float* __restrict__ ah1, const float* __restrict__ ah2,
    const int* __restrict__ starts, const int* __restrict__ counts,
    const int* __restrict__ edges) {
  int row = blockIdx.x;
  int st = row >> 14;
  int base = row & ~511;  // row index of (st,b) block start
  int t = threadIdx.x;
  __shared__ int jl[512];
  __shared__ float el[512];
  __shared__ float red[2];
  int start = starts[row], cnt = counts[row];
  const int* ed = edges + (size_t)st * CAP + start;
  float a1v = ah1[row];
  const float* ah2b = ah2 + base;
  float lmax = -1e30f;
  for (int k = t; k < cnt; k += 128) {
    int jj = ed[k];
    float e = a1v + ah2b[jj];
    e = e >= 0.f ? e : 0.2f * e;  // leaky_relu 0.2
    jl[k] = jj;
    el[k] = e;
    lmax = fmaxf(lmax, e);
  }
  for (int off = 32; off; off >>= 1) lmax = fmaxf(lmax, __shfl_xor(lmax, off, 64));
  if ((t & 63) == 0) red[t >> 6] = lmax;
  __syncthreads();
  float m = fmaxf(red[0], red[1]);
  __syncthreads();
  float lsum = 0.f;
  for (int k = t; k < cnt; k += 128) {
    float w = __expf(el[k] - m);
    el[k] = w;
    lsum += w;
  }
  for (int off = 32; off; off >>= 1) lsum += __shfl_xor(lsum, off, 64);
  if ((t & 63) == 0) red[t >> 6] = lsum;
  __syncthreads();
  float Z = red[0] + red[1];
  float inv = cnt > 0 ? 1.0f / Z : 0.f;
  float acc = 0.f;
  const float* wgb = whg + (size_t)base * 128;
  for (int k = 0; k < cnt; ++k) {
    acc = fmaf(el[k], wgb[(size_t)jl[k] * 128 + t], acc);
  }
  acc *= inv;
  float v = wh[(size_t)row * 128 + t] + acc;
  wh[(size_t)row * 128 + t] = v > 0.f ? v : __expf(v) - 1.f;  // elu
}

// ---------------------------------------------------------------------------
// mid[side][b][c] = sum_i (wh[2s][b][i][c] + wh[2s+1][b][i][c]). grid 512x256.
__global__ void k_mid(const float* __restrict__ wh, float* __restrict__ mid) {
  int blk = blockIdx.x;
  int side = blk >> 8, b = (blk >> 3) & 31, ch = blk & 7;
  int t = threadIdx.x;
  int c = t & 127, hh = t >> 7;
  float sum = 0.f;
  size_t b0 = ((size_t)(2 * side) * 16384 + b * 512) * 128;
  size_t b1 = ((size_t)(2 * side + 1) * 16384 + b * 512) * 128;
  for (int q = 0; q < 32; ++q) {
    int i = ch * 64 + hh * 32 + q;
    sum += wh[b0 + (size_t)i * 128 + c];
    sum += wh[b1 + (size_t)i * 128 + c];
  }
  atomicAdd(&mid[(side * 32 + b) * 128 + c], sum);
}

__global__ void k_out(const float* __restrict__ mid,
                      const float* __restrict__ Wout,
                      const float* __restrict__ bout, float* __restrict__ e12) {
  int sb = blockIdx.x;  // 0..63  (side*32+b)
  int o = threadIdx.x;  // 0..63
  const float* m = mid + sb * 128;
  float acc = bout[o];
  for (int k = 0; k < 128; ++k) acc = fmaf(m[k], Wout[k * 64 + o], acc);
  e12[sb * 64 + o] = acc;
}

__global__ void k_cos(const float* __restrict__ e12, float* __restrict__ out) {
  int b = threadIdx.x;
  if (b >= 32) return;
  const float* e1 = e12 + b * 64;
  const float* e2 = e12 + 2048 + b * 64;
  float d = 0.f, n1 = 0.f, n2 = 0.f;
  for (int o = 0; o < 64; ++o) {
    float a = e1[o], c = e2[o];
    d = fmaf(a, c, d);
    n1 = fmaf(a, a, n1);
    n2 = fmaf(c, c, n2);
  }
  float nn = fmaxf(sqrtf(n1), 1e-12f) * fmaxf(sqrtf(n2), 1e-12f);
  out[b] = 0.5f * (1.f + d / nn);
}

// ---------------------------------------------------------------------------
extern "C" void kernel_launch(void* const* d_in, const int* in_sizes, int n_in,
                              void* d_out, int out_size, void* d_ws,
                              size_t ws_size, hipStream_t stream) {
  const float* CFG1 = (const float*)d_in[0];
  const float* LIT1 = (const float*)d_in[2];
  const float* SEM1 = (const float*)d_in[3];
  const float* CFG2 = (const float*)d_in[4];
  const float* LIT2 = (const float*)d_in[6];
  const float* SEM2 = (const float*)d_in[7];
  const float* WL1 = (const float*)d_in[8];
  const float* GK1 = (const float*)d_in[9];
  const float* GRK1 = (const float*)d_in[10];
  const float* GB1 = (const float*)d_in[11];
  const float* WL2 = (const float*)d_in[12];
  const float* GK2 = (const float*)d_in[13];
  const float* GRK2 = (const float*)d_in[14];
  const float* GB2 = (const float*)d_in[15];
  const float* A1W = (const float*)d_in[16];
  const float* A1B = (const float*)d_in[17];
  const float* A2W = (const float*)d_in[18];
  const float* A2B = (const float*)d_in[19];
  const float* WG = (const float*)d_in[20];
  const float* WOUT = (const float*)d_in[21];
  const float* BOUT = (const float*)d_in[22];

  float* ws = (float*)d_ws;
  float* wh = ws;             // 8388608
  float* whg = wh + 8388608;  // 8388608 (xp aliases; tail aliases csr scratch)
  float* xp = whg;            // [2][16384][192] = 6291456 < 8388608
  // csr scratch in whg tail (free during xp phase, dead before k_whg)
  int* ccolchunk = (int*)(whg + 6291456);  // 262144
  int* chunkbase = ccolchunk + 262144;     // 262144
  float* x = whg + 8388608;                // 4194304
  float* ah1 = x + 4194304;                // 65536
  float* ah2 = ah1 + 65536;                // 65536
  float* mid = ah2 + 65536;                // 8192
  float* e12 = mid + 8192;                 // 4096
  int* starts = (int*)(e12 + 4096);        // 65536
  int* counts = starts + 65536;            // 65536
  int* cursors = counts + 65536;           // 64
  int* edges = cursors + 64;               // 4*CAP

  hipMemsetAsync(cursors, 0, 64 * 4, stream);
  hipMemsetAsync(mid, 0, 8192 * 4, stream);

  k_data<<<1024, 64, 0, stream>>>(LIT1, SEM1, LIT2, SEM2, WL1, GK1, GB1, WL2,
                                  GK2, GB2, x, xp);
  k_gru<<<64, 64, 0, stream>>>(xp, GRK1, GB1, GRK2, GB2, x);
  k_count<<<512, 256, 0, stream>>>(CFG1, CFG2, counts, ccolchunk);
  k_alloc<<<256, 256, 0, stream>>>(ccolchunk, counts, starts, chunkbase,
                                   cursors);
  k_fill<<<512, 256, 0, stream>>>(CFG1, CFG2, starts, chunkbase, edges);
  k_init<<<8192, 256, 0, stream>>>(x, wh);
  for (int step = 0; step < 3; ++step) {
    k_whg<<<1024, 64, 0, stream>>>(wh, WG, A1W, A1B, A2W, A2B, whg, ah1, ah2);
    k_attn<<<65536, 128, 0, stream>>>(wh, whg, ah1, ah2, starts, counts, edges);
  }
  k_mid<<<512, 256, 0, stream>>>(wh, mid);
  k_out<<<64, 64, 0, stream>>>(mid, WOUT, BOUT, e12);
  k_cos<<<1, 64, 0, stream>>>(e12, (float*)d_out);
}

// Round 4
// 1057.610 us; speedup vs baseline: 1.8040x; 1.0344x over previous
//
#include <hip/hip_runtime.h>

// Problem constants
#define BB 32
#define NNODE 512
#define EE 128
#define CAP 786432  // edge capacity per stream (expected ~419K)

typedef float v2f __attribute__((ext_vector_type(2)));
__device__ __forceinline__ v2f fma2(v2f a, v2f b, v2f c) {
  return __builtin_elementwise_fma(a, b, c);
}

__device__ __forceinline__ float sigm(float x) { return 1.0f / (1.0f + __expf(-x)); }
__device__ __forceinline__ float tanh_f(float x) {
  x = fminf(20.f, fmaxf(-20.f, x));
  float t = __expf(-2.f * x);
  return (1.f - t) / (1.f + t);
}

// ---------------------------------------------------------------------------
// x[:, :, 0:64] = relu(LIT @ W_lit);  xp = SEM @ gru_k + gru_b[0]
// grid 1024 x 64.  bid>>1 = 64-row block, bid&1 = col half.
__global__ __launch_bounds__(64, 1) void k_data(
    const float* __restrict__ lit1, const float* __restrict__ sem1,
    const float* __restrict__ lit2, const float* __restrict__ sem2,
    const float* __restrict__ wl1, const float* __restrict__ gk1,
    const float* __restrict__ gb1, const float* __restrict__ wl2,
    const float* __restrict__ gk2, const float* __restrict__ gb2,
    float* __restrict__ x, float* __restrict__ xp) {
  __shared__ float stage[64 * 65];
  int bid = blockIdx.x;
  int rowblk = bid >> 1, half = bid & 1;
  int grow0 = rowblk * 64;
  int side = grow0 >> 14;
  int lrow0 = grow0 & 16383;
  const float* lit = side ? lit2 : lit1;
  const float* sem = side ? sem2 : sem1;
  const float* wl = side ? wl2 : wl1;
  const float* gk = side ? gk2 : gk1;
  const float* gb = side ? gb2 : gb1;
  int tid = threadIdx.x;
  int grow = grow0 + tid;

  // ---- literal matmul: 64 rows x 32 cols (this half) ----
  {
    const float4* lit4 = (const float4*)(lit + (size_t)lrow0 * 64);
#pragma unroll
    for (int p = 0; p < 16; ++p) {
      int s = p * 64 + tid;
      int r = s >> 4, q = s & 15;
      float4 v = lit4[r * 16 + q];
      stage[r * 65 + 4 * q + 0] = v.x;
      stage[r * 65 + 4 * q + 1] = v.y;
      stage[r * 65 + 4 * q + 2] = v.z;
      stage[r * 65 + 4 * q + 3] = v.w;
    }
    v2f acc[16];
#pragma unroll
    for (int c = 0; c < 16; ++c) acc[c] = (v2f){0.f, 0.f};
    const float4* wl4 = (const float4*)wl;  // [64][16] f4
    for (int i = 0; i < 64; ++i) {
      float rv = stage[tid * 65 + i];
      v2f rv2 = {rv, rv};
#pragma unroll
      for (int c4 = 0; c4 < 8; ++c4) {
        float4 w = wl4[i * 16 + half * 8 + c4];
        acc[2 * c4 + 0] = fma2(rv2, (v2f){w.x, w.y}, acc[2 * c4 + 0]);
        acc[2 * c4 + 1] = fma2(rv2, (v2f){w.z, w.w}, acc[2 * c4 + 1]);
      }
    }
    float4* x4 = (float4*)x;
#pragma unroll
    for (int c4 = 0; c4 < 8; ++c4) {
      float4 o;
      o.x = fmaxf(acc[2 * c4].x, 0.f);
      o.y = fmaxf(acc[2 * c4].y, 0.f);
      o.z = fmaxf(acc[2 * c4 + 1].x, 0.f);
      o.w = fmaxf(acc[2 * c4 + 1].y, 0.f);
      x4[(size_t)grow * 32 + half * 8 + c4] = o;
    }
  }
  // ---- semantic input projection: 64 rows x 96 cols (this half) ----
  {
    const float4* sem4 = (const float4*)(sem + (size_t)lrow0 * 64);
#pragma unroll
    for (int p = 0; p < 16; ++p) {
      int s = p * 64 + tid;
      int r = s >> 4, q = s & 15;
      float4 v = sem4[r * 16 + q];
      stage[r * 65 + 4 * q + 0] = v.x;
      stage[r * 65 + 4 * q + 1] = v.y;
      stage[r * 65 + 4 * q + 2] = v.z;
      stage[r * 65 + 4 * q + 3] = v.w;
    }
    v2f acc2[48];
#pragma unroll
    for (int c = 0; c < 48; ++c)
      acc2[c] = (v2f){gb[half * 96 + 2 * c], gb[half * 96 + 2 * c + 1]};
    const float4* gk4 = (const float4*)gk;  // [64][48] f4
    for (int i = 0; i < 64; ++i) {
      float rv = stage[tid * 65 + i];
      v2f rv2 = {rv, rv};
#pragma unroll
      for (int c4 = 0; c4 < 24; ++c4) {
        float4 w = gk4[i * 48 + half * 24 + c4];
        acc2[2 * c4 + 0] = fma2(rv2, (v2f){w.x, w.y}, acc2[2 * c4 + 0]);
        acc2[2 * c4 + 1] = fma2(rv2, (v2f){w.z, w.w}, acc2[2 * c4 + 1]);
      }
    }
    float4* xp4 = (float4*)xp;
#pragma unroll
    for (int c4 = 0; c4 < 24; ++c4) {
      float4 o;
      o.x = acc2[2 * c4].x;
      o.y = acc2[2 * c4].y;
      o.z = acc2[2 * c4 + 1].x;
      o.w = acc2[2 * c4 + 1].y;
      xp4[(size_t)grow * 48 + half * 24 + c4] = o;
    }
  }
}

// ---------------------------------------------------------------------------
// GRU scan (Keras reset_after). One block (4 waves) per (side,batch) chain.
// thread = (output j = 16*wave + lane&15, kslice = (lane>>4)&3).
// Per step: 4x ds_read_b128 (K-slice of h), 24 pk-FMA, shfl-xor reduce,
// redundant activations (all 4 dup lanes), ks==0 lanes write h.
// xp staged via LDS in 16-step chunks (reg prefetch at chunk start, LDS
// write at chunk end => HBM latency fully hidden). grid 64 x 256.
__global__ __launch_bounds__(256, 1) void k_gru(
    const float* __restrict__ xp, const float* __restrict__ rk1,
    const float* __restrict__ b1, const float* __restrict__ rk2,
    const float* __restrict__ b2, float* __restrict__ x) {
  int blk = blockIdx.x;
  int side = blk >> 5, b = blk & 31;
  int tid = threadIdx.x;
  int wave = tid >> 6;
  int lane = tid & 63;
  int jj = (lane & 15) + 16 * wave;  // output index 0..63
  int ks = (lane >> 4) & 3;          // K-slice 0..3
  const float* rk = side ? rk2 : rk1;
  const float* bbp = side ? b2 : b1;
  // per-thread recurrent weights: rows 16ks..16ks+15, col jj, 3 gates
  v2f wz[8], wr[8], wv[8];
#pragma unroll
  for (int i = 0; i < 8; ++i) {
    int r0 = 16 * ks + 2 * i, r1 = r0 + 1;
    wz[i] = (v2f){rk[r0 * 192 + jj], rk[r1 * 192 + jj]};
    wr[i] = (v2f){rk[r0 * 192 + 64 + jj], rk[r1 * 192 + 64 + jj]};
    wv[i] = (v2f){rk[r0 * 192 + 128 + jj], rk[r1 * 192 + 128 + jj]};
  }
  float bz = bbp[192 + jj], brr = bbp[192 + 64 + jj], bv = bbp[192 + 128 + jj];

  __shared__ float hs[2][64];
  __shared__ float xpb[2][16 * 192];  // 24 KB double-buffered xp chunks
  if (tid < 64) hs[0][tid] = 0.f;

  const float* xpr = xp + (size_t)(side * 16384 + b * 512) * 192;
  float* xrow = x + (size_t)(side * 16384 + b * 512) * 128;

  // load chunk 0 directly
  {
    const float4* src = (const float4*)xpr;
    float4* dst = (float4*)xpb[0];
#pragma unroll
    for (int q = 0; q < 3; ++q) dst[q * 256 + tid] = src[q * 256 + tid];
  }
  __syncthreads();

  int cur = 0;
  for (int tc = 0; tc < 32; ++tc) {
    // issue prefetch of next chunk into registers (consumed at chunk end)
    float4 pf0, pf1, pf2;
    if (tc + 1 < 32) {
      const float4* src = (const float4*)(xpr + (size_t)(tc + 1) * 3072);
      pf0 = src[0 * 256 + tid];
      pf1 = src[1 * 256 + tid];
      pf2 = src[2 * 256 + tid];
    }
#pragma unroll
    for (int tt = 0; tt < 16; ++tt) {
      int t = tc * 16 + tt;
      int hb = t & 1;
      const float* hsrc = hs[hb];
      const float* xc = &xpb[cur][tt * 192];
      float cxz = xc[jj], cxr = xc[64 + jj], cxv = xc[128 + jj];
      float hold = hsrc[jj];
      const float4* h4 = (const float4*)(hsrc + 16 * ks);
      v2f az = {0.f, 0.f}, ar = {0.f, 0.f}, av = {0.f, 0.f};
#pragma unroll
      for (int c = 0; c < 4; ++c) {
        float4 h = h4[c];
        v2f hlo = {h.x, h.y}, hhi = {h.z, h.w};
        az = fma2(hlo, wz[2 * c], az);
        az = fma2(hhi, wz[2 * c + 1], az);
        ar = fma2(hlo, wr[2 * c], ar);
        ar = fma2(hhi, wr[2 * c + 1], ar);
        av = fma2(hlo, wv[2 * c], av);
        av = fma2(hhi, wv[2 * c + 1], av);
      }
      float saz = az.x + az.y, sar = ar.x + ar.y, sav = av.x + av.y;
      saz += __shfl_xor(saz, 16, 64);
      saz += __shfl_xor(saz, 32, 64);
      sar += __shfl_xor(sar, 16, 64);
      sar += __shfl_xor(sar, 32, 64);
      sav += __shfl_xor(sav, 16, 64);
      sav += __shfl_xor(sav, 32, 64);
      float z = sigm(cxz + saz + bz);
      float r = sigm(cxr + sar + brr);
      float hh = tanh_f(cxv + r * (sav + bv));
      float hnew = fmaf(z, hold - hh, hh);  // z*h + (1-z)*hh
      if (ks == 0) {
        hs[hb ^ 1][jj] = hnew;
        xrow[(size_t)t * 128 + 64 + jj] = hnew;
      }
      __syncthreads();
    }
    // write prefetched chunk into back buffer (loads long complete)
    if (tc + 1 < 32) {
      float4* dst = (float4*)xpb[cur ^ 1];
      dst[0 * 256 + tid] = pf0;
      dst[1 * 256 + tid] = pf1;
      dst[2 * 256 + tid] = pf2;
      __syncthreads();
    }
    cur ^= 1;
  }
}

// ---------------------------------------------------------------------------
// CSR/CSC build, pass 1: counts.  grid 512 x 256.
// Block = (side s, batch b, chunk ch of 64 rows). All counting in LDS.
__global__ __launch_bounds__(256, 1) void k_count(
    const float* __restrict__ A1, const float* __restrict__ A2,
    int* __restrict__ counts, int* __restrict__ ccolchunk) {
  int bid = blockIdx.x;
  int s = bid >> 8, b = (bid >> 3) & 31, ch = bid & 7;
  const float* A = s ? A2 : A1;
  const float4* A4 = (const float4*)(A + ((size_t)b * 512 + ch * 64) * 512);
  int t = threadIdx.x;
  __shared__ int ccol[512];
  __shared__ int crow[64];
  ccol[t] = 0;
  ccol[t + 256] = 0;
  if (t < 64) crow[t] = 0;
  __syncthreads();
#pragma unroll
  for (int it = 0; it < 32; ++it) {
    int idx = it * 256 + t;
    int r = idx >> 7, c4 = idx & 127;
    float4 v = A4[idx];
    int n = 0;
    if (v.x != 0.f) { atomicAdd(&ccol[4 * c4 + 0], 1); n++; }
    if (v.y != 0.f) { atomicAdd(&ccol[4 * c4 + 1], 1); n++; }
    if (v.z != 0.f) { atomicAdd(&ccol[4 * c4 + 2], 1); n++; }
    if (v.w != 0.f) { atomicAdd(&ccol[4 * c4 + 3], 1); n++; }
    if (n) atomicAdd(&crow[r], n);
  }
  __syncthreads();
  if (t < 64) counts[(2 * s) * 16384 + b * 512 + ch * 64 + t] = crow[t];
  int cbase = ((s * 32 + b) * 8 + ch) * 512;
  ccolchunk[cbase + t] = ccol[t];
  ccolchunk[cbase + t + 256] = ccol[t + 256];
}

// ---------------------------------------------------------------------------
// CSR/CSC build, pass 2: offsets. grid 256 x 256.
// bid<128: fwd rows; bid>=128: rev cols (+ per-chunk bases).
__global__ __launch_bounds__(256, 1) void k_alloc(
    const int* __restrict__ ccolchunk, int* __restrict__ counts,
    int* __restrict__ starts, int* __restrict__ chunkbase,
    int* __restrict__ cursors) {
  int bid = blockIdx.x;
  int t = threadIdx.x;
  int lane = t & 63, wave = t >> 6;
  __shared__ int wsum[4];
  __shared__ int gbase;

  int c, cursor_idx, out_idx;
  int pchunk[8];
  if (bid < 128) {
    int fr = bid * 256 + t;  // 0..32767
    int s = fr >> 14;
    out_idx = (2 * s) * 16384 + (fr & 16383);
    cursor_idx = 2 * s;
    c = counts[out_idx];
  } else {
    int cid = (bid - 128) * 256 + t;  // 0..32767 -> (s,b,j)
    int s = cid >> 14, b = (cid >> 9) & 31, j = cid & 511;
    out_idx = (2 * s + 1) * 16384 + b * 512 + j;
    cursor_idx = 2 * s + 1;
    c = 0;
#pragma unroll
    for (int ch = 0; ch < 8; ++ch) {
      pchunk[ch] = ccolchunk[((s * 32 + b) * 8 + ch) * 512 + j];
      c += pchunk[ch];
    }
    counts[out_idx] = c;
  }
  // block exclusive scan
  int v = c;
#pragma unroll
  for (int d = 1; d < 64; d <<= 1) {
    int o = __shfl_up(v, d, 64);
    if (lane >= d) v += o;
  }
  if (lane == 63) wsum[wave] = v;
  __syncthreads();
  int wbase = 0;
  for (int w = 0; w < wave; ++w) wbase += w < 4 ? wsum[w] : 0;
  int tot = wsum[0] + wsum[1] + wsum[2] + wsum[3];
  if (t == 0) gbase = atomicAdd(&cursors[cursor_idx], tot);
  __syncthreads();
  int start = gbase + wbase + v - c;
  starts[out_idx] = start;
  if (bid >= 128) {
    int cid = (bid - 128) * 256 + t;
    int s = cid >> 14, b = (cid >> 9) & 31, j = cid & 511;
    int run = start;
#pragma unroll
    for (int ch = 0; ch < 8; ++ch) {
      chunkbase[((s * 32 + b) * 8 + ch) * 512 + j] = run;
      run += pchunk[ch];
    }
  }
}

// ---------------------------------------------------------------------------
// CSR/CSC build, pass 3: fill. grid 512 x 256. LDS-atomic positions only.
__global__ __launch_bounds__(256, 1) void k_fill(
    const float* __restrict__ A1, const float* __restrict__ A2,
    const int* __restrict__ starts, const int* __restrict__ chunkbase,
    int* __restrict__ edges) {
  int bid = blockIdx.x;
  int s = bid >> 8, b = (bid >> 3) & 31, ch = bid & 7;
  const float* A = s ? A2 : A1;
  const float4* A4 = (const float4*)(A + ((size_t)b * 512 + ch * 64) * 512);
  int t = threadIdx.x;
  __shared__ int ccol[512];  // local position within (chunk, col)
  __shared__ int cb[512];    // chunkbase for this block
  __shared__ int crow[64];
  __shared__ int sf[64];
  ccol[t] = 0;
  ccol[t + 256] = 0;
  int cbase = ((s * 32 + b) * 8 + ch) * 512;
  cb[t] = chunkbase[cbase + t];
  cb[t + 256] = chunkbase[cbase + t + 256];
  if (t < 64) {
    crow[t] = 0;
    sf[t] = starts[(2 * s) * 16384 + b * 512 + ch * 64 + t];
  }
  __syncthreads();
  int* efwd = edges + (size_t)(2 * s) * CAP;
  int* erev = edges + (size_t)(2 * s + 1) * CAP;
#pragma unroll
  for (int it = 0; it < 32; ++it) {
    int idx = it * 256 + t;
    int r = idx >> 7, c4 = idx & 127;
    float4 v = A4[idx];
    float vv[4] = {v.x, v.y, v.z, v.w};
    int i = ch * 64 + r;
#pragma unroll
    for (int e = 0; e < 4; ++e) {
      if (vv[e] != 0.f) {
        int j = 4 * c4 + e;
        int lp = atomicAdd(&ccol[j], 1);
        int ri = cb[j] + lp;
        if (ri < CAP) erev[ri] = i;
        int fp = atomicAdd(&crow[r], 1);
        int fi = sf[r] + fp;
        if (fi < CAP) efwd[fi] = j;
      }
    }
  }
}

// ---------------------------------------------------------------------------
// wh[st] = relu(x[side(st)]). grid 8192 x 256 over f4.
__global__ void k_init(const float* __restrict__ x, float* __restrict__ wh) {
  int idx = blockIdx.x * 256 + threadIdx.x;
  int st = idx >> 19;  // 524288 f4 per stream
  int loc = idx & 524287;
  int side = st >> 1;
  float4 v = ((const float4*)x)[(size_t)side * 524288 + loc];
  v.x = fmaxf(v.x, 0.f);
  v.y = fmaxf(v.y, 0.f);
  v.z = fmaxf(v.z, 0.f);
  v.w = fmaxf(v.w, 0.f);
  ((float4*)wh)[idx] = v;
}

// ---------------------------------------------------------------------------
// whg = wh @ W_g;  ah1 = wh@a1_w + a1_b;  ah2 = wh@a2_w + a2_b
// grid 1024 x 64; one wave = 64 rows, packed-f32 acc, W_g via uniform loads.
__global__ __launch_bounds__(64, 1) void k_whg(
    const float* __restrict__ wh, const float* __restrict__ Wg,
    const float* __restrict__ a1w, const float* __restrict__ a1b,
    const float* __restrict__ a2w, const float* __restrict__ a2b,
    float* __restrict__ whg, float* __restrict__ ah1, float* __restrict__ ah2) {
  __shared__ float stage[64 * 129];
  int rowbase = blockIdx.x * 64;
  int tid = threadIdx.x;
  const float4* wh4 = (const float4*)(wh + (size_t)rowbase * 128);
#pragma unroll
  for (int p = 0; p < 32; ++p) {
    int s = p * 64 + tid;
    int r = s >> 5, q = s & 31;
    float4 v = wh4[r * 32 + q];
    stage[r * 129 + 4 * q + 0] = v.x;
    stage[r * 129 + 4 * q + 1] = v.y;
    stage[r * 129 + 4 * q + 2] = v.z;
    stage[r * 129 + 4 * q + 3] = v.w;
  }
  v2f acc[64];
#pragma unroll
  for (int c = 0; c < 64; ++c) acc[c] = (v2f){0.f, 0.f};
  float p1 = a1b[0], p2 = a2b[0];
  const float4* Wg4 = (const float4*)Wg;  // [128][32] f4
  for (int i = 0; i < 128; ++i) {
    float rv = stage[tid * 129 + i];
    v2f rv2 = {rv, rv};
    p1 = fmaf(rv, a1w[i], p1);
    p2 = fmaf(rv, a2w[i], p2);
#pragma unroll
    for (int c4 = 0; c4 < 32; ++c4) {
      float4 w = Wg4[i * 32 + c4];
      acc[2 * c4 + 0] = fma2(rv2, (v2f){w.x, w.y}, acc[2 * c4 + 0]);
      acc[2 * c4 + 1] = fma2(rv2, (v2f){w.z, w.w}, acc[2 * c4 + 1]);
    }
  }
  int grow = rowbase + tid;
  float4* o4 = (float4*)(whg + (size_t)grow * 128);
#pragma unroll
  for (int c4 = 0; c4 < 32; ++c4) {
    float4 o;
    o.x = acc[2 * c4].x;
    o.y = acc[2 * c4].y;
    o.z = acc[2 * c4 + 1].x;
    o.w = acc[2 * c4 + 1].y;
    o4[c4] = o;
  }
  ah1[grow] = p1;
  ah2[grow] = p2;
}

// ---------------------------------------------------------------------------
// Per-row edge softmax + aggregate + elu update. grid 65536 x 128.
__global__ __launch_bounds__(128, 1) void k_attn(
    float* __restrict__ wh, const float* __restrict__ whg,
    const float* __restrict__ ah1, const float* __restrict__ ah2,
    const int* __restrict__ starts, const int* __restrict__ counts,
    const int* __restrict__ edges) {
  int row = blockIdx.x;
  int st = row >> 14;
  int base = row & ~511;  // row index of (st,b) block start
  int t = threadIdx.x;
  __shared__ int jl[512];
  __shared__ float el[512];
  __shared__ float red[2];
  int start = starts[row], cnt = counts[row];
  const int* ed = edges + (size_t)st * CAP + start;
  float a1v = ah1[row];
  const float* ah2b = ah2 + base;
  float lmax = -1e30f;
  for (int k = t; k < cnt; k += 128) {
    int jj = ed[k];
    float e = a1v + ah2b[jj];
    e = e >= 0.f ? e : 0.2f * e;  // leaky_relu 0.2
    jl[k] = jj;
    el[k] = e;
    lmax = fmaxf(lmax, e);
  }
  for (int off = 32; off; off >>= 1) lmax = fmaxf(lmax, __shfl_xor(lmax, off, 64));
  if ((t & 63) == 0) red[t >> 6] = lmax;
  __syncthreads();
  float m = fmaxf(red[0], red[1]);
  __syncthreads();
  float lsum = 0.f;
  for (int k = t; k < cnt; k += 128) {
    float w = __expf(el[k] - m);
    el[k] = w;
    lsum += w;
  }
  for (int off = 32; off; off >>= 1) lsum += __shfl_xor(lsum, off, 64);
  if ((t & 63) == 0) red[t >> 6] = lsum;
  __syncthreads();
  float Z = red[0] + red[1];
  float inv = cnt > 0 ? 1.0f / Z : 0.f;
  // 4-way unrolled gather: independent acc chains, batched loads
  float a0 = 0.f, a1 = 0.f, a2 = 0.f, a3 = 0.f;
  const float* wgb = whg + (size_t)base * 128;
  int k = 0;
  for (; k + 4 <= cnt; k += 4) {
    float w0 = el[k], w1 = el[k + 1], w2 = el[k + 2], w3 = el[k + 3];
    int j0 = jl[k], j1 = jl[k + 1], j2 = jl[k + 2], j3 = jl[k + 3];
    a0 = fmaf(w0, wgb[(size_t)j0 * 128 + t], a0);
    a1 = fmaf(w1, wgb[(size_t)j1 * 128 + t], a1);
    a2 = fmaf(w2, wgb[(size_t)j2 * 128 + t], a2);
    a3 = fmaf(w3, wgb[(size_t)j3 * 128 + t], a3);
  }
  for (; k < cnt; ++k) a0 = fmaf(el[k], wgb[(size_t)jl[k] * 128 + t], a0);
  float acc = ((a0 + a1) + (a2 + a3)) * inv;
  float v = wh[(size_t)row * 128 + t] + acc;
  wh[(size_t)row * 128 + t] = v > 0.f ? v : __expf(v) - 1.f;  // elu
}

// ---------------------------------------------------------------------------
// mid[side][b][c] = sum_i (wh[2s][b][i][c] + wh[2s+1][b][i][c]). grid 512x256.
__global__ void k_mid(const float* __restrict__ wh, float* __restrict__ mid) {
  int blk = blockIdx.x;
  int side = blk >> 8, b = (blk >> 3) & 31, ch = blk & 7;
  int t = threadIdx.x;
  int c = t & 127, hh = t >> 7;
  float sum = 0.f;
  size_t b0 = ((size_t)(2 * side) * 16384 + b * 512) * 128;
  size_t b1 = ((size_t)(2 * side + 1) * 16384 + b * 512) * 128;
  for (int q = 0; q < 32; ++q) {
    int i = ch * 64 + hh * 32 + q;
    sum += wh[b0 + (size_t)i * 128 + c];
    sum += wh[b1 + (size_t)i * 128 + c];
  }
  atomicAdd(&mid[(side * 32 + b) * 128 + c], sum);
}

__global__ void k_out(const float* __restrict__ mid,
                      const float* __restrict__ Wout,
                      const float* __restrict__ bout, float* __restrict__ e12) {
  int sb = blockIdx.x;  // 0..63  (side*32+b)
  int o = threadIdx.x;  // 0..63
  const float* m = mid + sb * 128;
  float acc = bout[o];
  for (int k = 0; k < 128; ++k) acc = fmaf(m[k], Wout[k * 64 + o], acc);
  e12[sb * 64 + o] = acc;
}

__global__ void k_cos(const float* __restrict__ e12, float* __restrict__ out) {
  int b = threadIdx.x;
  if (b >= 32) return;
  const float* e1 = e12 + b * 64;
  const float* e2 = e12 + 2048 + b * 64;
  float d = 0.f, n1 = 0.f, n2 = 0.f;
  for (int o = 0; o < 64; ++o) {
    float a = e1[o], c = e2[o];
    d = fmaf(a, c, d);
    n1 = fmaf(a, a, n1);
    n2 = fmaf(c, c, n2);
  }
  float nn = fmaxf(sqrtf(n1), 1e-12f) * fmaxf(sqrtf(n2), 1e-12f);
  out[b] = 0.5f * (1.f + d / nn);
}

// ---------------------------------------------------------------------------
extern "C" void kernel_launch(void* const* d_in, const int* in_sizes, int n_in,
                              void* d_out, int out_size, void* d_ws,
                              size_t ws_size, hipStream_t stream) {
  const float* CFG1 = (const float*)d_in[0];
  const float* LIT1 = (const float*)d_in[2];
  const float* SEM1 = (const float*)d_in[3];
  const float* CFG2 = (const float*)d_in[4];
  const float* LIT2 = (const float*)d_in[6];
  const float* SEM2 = (const float*)d_in[7];
  const float* WL1 = (const float*)d_in[8];
  const float* GK1 = (const float*)d_in[9];
  const float* GRK1 = (const float*)d_in[10];
  const float* GB1 = (const float*)d_in[11];
  const float* WL2 = (const float*)d_in[12];
  const float* GK2 = (const float*)d_in[13];
  const float* GRK2 = (const float*)d_in[14];
  const float* GB2 = (const float*)d_in[15];
  const float* A1W = (const float*)d_in[16];
  const float* A1B = (const float*)d_in[17];
  const float* A2W = (const float*)d_in[18];
  const float* A2B = (const float*)d_in[19];
  const float* WG = (const float*)d_in[20];
  const float* WOUT = (const float*)d_in[21];
  const float* BOUT = (const float*)d_in[22];

  float* ws = (float*)d_ws;
  float* wh = ws;             // 8388608
  float* whg = wh + 8388608;  // 8388608 (xp aliases; tail aliases csr scratch)
  float* xp = whg;            // [2][16384][192] = 6291456 < 8388608
  // csr scratch in whg tail (free during xp phase, dead before k_whg)
  int* ccolchunk = (int*)(whg + 6291456);  // 262144
  int* chunkbase = ccolchunk + 262144;     // 262144
  float* x = whg + 8388608;                // 4194304
  float* ah1 = x + 4194304;                // 65536
  float* ah2 = ah1 + 65536;                // 65536
  float* mid = ah2 + 65536;                // 8192
  float* e12 = mid + 8192;                 // 4096
  int* starts = (int*)(e12 + 4096);        // 65536
  int* counts = starts + 65536;            // 65536
  int* cursors = counts + 65536;           // 64
  int* edges = cursors + 64;               // 4*CAP

  hipMemsetAsync(cursors, 0, 64 * 4, stream);
  hipMemsetAsync(mid, 0, 8192 * 4, stream);

  k_data<<<1024, 64, 0, stream>>>(LIT1, SEM1, LIT2, SEM2, WL1, GK1, GB1, WL2,
                                  GK2, GB2, x, xp);
  k_gru<<<64, 256, 0, stream>>>(xp, GRK1, GB1, GRK2, GB2, x);
  k_count<<<512, 256, 0, stream>>>(CFG1, CFG2, counts, ccolchunk);
  k_alloc<<<256, 256, 0, stream>>>(ccolchunk, counts, starts, chunkbase,
                                   cursors);
  k_fill<<<512, 256, 0, stream>>>(CFG1, CFG2, starts, chunkbase, edges);
  k_init<<<8192, 256, 0, stream>>>(x, wh);
  for (int step = 0; step < 3; ++step) {
    k_whg<<<1024, 64, 0, stream>>>(wh, WG, A1W, A1B, A2W, A2B, whg, ah1, ah2);
    k_attn<<<65536, 128, 0, stream>>>(wh, whg, ah1, ah2, starts, counts, edges);
  }
  k_mid<<<512, 256, 0, stream>>>(wh, mid);
  k_out<<<64, 64, 0, stream>>>(mid, WOUT, BOUT, e12);
  k_cos<<<1, 64, 0, stream>>>(e12, (float*)d_out);
}

// Round 5
// 982.234 us; speedup vs baseline: 1.9424x; 1.0767x over previous
//
#include <hip/hip_runtime.h>

// Problem constants
#define BB 32
#define NNODE 512
#define EE 128
#define CAP 786432  // edge capacity per stream (expected ~419K)

typedef float v2f __attribute__((ext_vector_type(2)));
__device__ __forceinline__ v2f fma2(v2f a, v2f b, v2f c) {
  return __builtin_elementwise_fma(a, b, c);
}

__device__ __forceinline__ float sigm(float x) { return 1.0f / (1.0f + __expf(-x)); }
__device__ __forceinline__ float tanh_f(float x) {
  x = fminf(20.f, fmaxf(-20.f, x));
  float t = __expf(-2.f * x);
  return (1.f - t) / (1.f + t);
}

// LDS-only barrier: wait LDS ops, do NOT drain vmcnt (stores/prefetch stay in flight)
#define LDS_BARRIER() asm volatile("s_waitcnt lgkmcnt(0)\n\ts_barrier" ::: "memory")

// ---------------------------------------------------------------------------
// wh[2s|2s+1][:, 0:64] = relu(LIT @ W_lit)  (written to both streams directly)
// xp = SEM @ gru_k + gru_b[0]
// grid 1024 x 64.  bid>>1 = 64-row block, bid&1 = col half.
__global__ __launch_bounds__(64, 1) void k_data(
    const float* __restrict__ lit1, const float* __restrict__ sem1,
    const float* __restrict__ lit2, const float* __restrict__ sem2,
    const float* __restrict__ wl1, const float* __restrict__ gk1,
    const float* __restrict__ gb1, const float* __restrict__ wl2,
    const float* __restrict__ gk2, const float* __restrict__ gb2,
    float* __restrict__ wh, float* __restrict__ xp) {
  __shared__ float stage[64 * 65];
  int bid = blockIdx.x;
  int rowblk = bid >> 1, half = bid & 1;
  int grow0 = rowblk * 64;
  int side = grow0 >> 14;
  int lrow0 = grow0 & 16383;
  const float* lit = side ? lit2 : lit1;
  const float* sem = side ? sem2 : sem1;
  const float* wl = side ? wl2 : wl1;
  const float* gk = side ? gk2 : gk1;
  const float* gb = side ? gb2 : gb1;
  int tid = threadIdx.x;

  // ---- literal matmul: 64 rows x 32 cols (this half) ----
  {
    const float4* lit4 = (const float4*)(lit + (size_t)lrow0 * 64);
#pragma unroll
    for (int p = 0; p < 16; ++p) {
      int s = p * 64 + tid;
      int r = s >> 4, q = s & 15;
      float4 v = lit4[r * 16 + q];
      stage[r * 65 + 4 * q + 0] = v.x;
      stage[r * 65 + 4 * q + 1] = v.y;
      stage[r * 65 + 4 * q + 2] = v.z;
      stage[r * 65 + 4 * q + 3] = v.w;
    }
    v2f acc[16];
#pragma unroll
    for (int c = 0; c < 16; ++c) acc[c] = (v2f){0.f, 0.f};
    const float4* wl4 = (const float4*)wl;  // [64][16] f4
    for (int i = 0; i < 64; ++i) {
      float rv = stage[tid * 65 + i];
      v2f rv2 = {rv, rv};
#pragma unroll
      for (int c4 = 0; c4 < 8; ++c4) {
        float4 w = wl4[i * 16 + half * 8 + c4];
        acc[2 * c4 + 0] = fma2(rv2, (v2f){w.x, w.y}, acc[2 * c4 + 0]);
        acc[2 * c4 + 1] = fma2(rv2, (v2f){w.z, w.w}, acc[2 * c4 + 1]);
      }
    }
    float4* w0 = (float4*)wh + ((size_t)(2 * side) * 16384 + lrow0 + tid) * 32;
    float4* w1 =
        (float4*)wh + ((size_t)(2 * side + 1) * 16384 + lrow0 + tid) * 32;
#pragma unroll
    for (int c4 = 0; c4 < 8; ++c4) {
      float4 o;
      o.x = fmaxf(acc[2 * c4].x, 0.f);
      o.y = fmaxf(acc[2 * c4].y, 0.f);
      o.z = fmaxf(acc[2 * c4 + 1].x, 0.f);
      o.w = fmaxf(acc[2 * c4 + 1].y, 0.f);
      w0[half * 8 + c4] = o;
      w1[half * 8 + c4] = o;
    }
  }
  // ---- semantic input projection: 64 rows x 96 cols (this half) ----
  {
    const float4* sem4 = (const float4*)(sem + (size_t)lrow0 * 64);
#pragma unroll
    for (int p = 0; p < 16; ++p) {
      int s = p * 64 + tid;
      int r = s >> 4, q = s & 15;
      float4 v = sem4[r * 16 + q];
      stage[r * 65 + 4 * q + 0] = v.x;
      stage[r * 65 + 4 * q + 1] = v.y;
      stage[r * 65 + 4 * q + 2] = v.z;
      stage[r * 65 + 4 * q + 3] = v.w;
    }
    v2f acc2[48];
#pragma unroll
    for (int c = 0; c < 48; ++c)
      acc2[c] = (v2f){gb[half * 96 + 2 * c], gb[half * 96 + 2 * c + 1]};
    const float4* gk4 = (const float4*)gk;  // [64][48] f4
    for (int i = 0; i < 64; ++i) {
      float rv = stage[tid * 65 + i];
      v2f rv2 = {rv, rv};
#pragma unroll
      for (int c4 = 0; c4 < 24; ++c4) {
        float4 w = gk4[i * 48 + half * 24 + c4];
        acc2[2 * c4 + 0] = fma2(rv2, (v2f){w.x, w.y}, acc2[2 * c4 + 0]);
        acc2[2 * c4 + 1] = fma2(rv2, (v2f){w.z, w.w}, acc2[2 * c4 + 1]);
      }
    }
    float4* xp4 = (float4*)xp;
    int grow = grow0 + tid;
#pragma unroll
    for (int c4 = 0; c4 < 24; ++c4) {
      float4 o;
      o.x = acc2[2 * c4].x;
      o.y = acc2[2 * c4].y;
      o.z = acc2[2 * c4 + 1].x;
      o.w = acc2[2 * c4 + 1].y;
      xp4[(size_t)grow * 48 + half * 24 + c4] = o;
    }
  }
}

// ---------------------------------------------------------------------------
// GRU scan (Keras reset_after). One block (4 waves) per (side,batch) chain.
// thread = (output j = 16*wave + lane&15, kslice = (lane>>4)&3).
// LDS-only barriers (no vmcnt drain); h outputs buffered 16 steps in regs and
// stored (relu'd, both streams) at chunk end. xp staged via LDS double buffer.
// grid 64 x 256.
__global__ __launch_bounds__(256, 1) void k_gru(
    const float* __restrict__ xp, const float* __restrict__ rk1,
    const float* __restrict__ b1, const float* __restrict__ rk2,
    const float* __restrict__ b2, float* __restrict__ wh) {
  int blk = blockIdx.x;
  int side = blk >> 5, b = blk & 31;
  int tid = threadIdx.x;
  int wave = tid >> 6;
  int lane = tid & 63;
  int jj = (lane & 15) + 16 * wave;  // output index 0..63
  int ks = (lane >> 4) & 3;          // K-slice 0..3
  const float* rk = side ? rk2 : rk1;
  const float* bbp = side ? b2 : b1;
  v2f wz[8], wr[8], wv[8];
#pragma unroll
  for (int i = 0; i < 8; ++i) {
    int r0 = 16 * ks + 2 * i, r1 = r0 + 1;
    wz[i] = (v2f){rk[r0 * 192 + jj], rk[r1 * 192 + jj]};
    wr[i] = (v2f){rk[r0 * 192 + 64 + jj], rk[r1 * 192 + 64 + jj]};
    wv[i] = (v2f){rk[r0 * 192 + 128 + jj], rk[r1 * 192 + 128 + jj]};
  }
  float bz = bbp[192 + jj], brr = bbp[192 + 64 + jj], bv = bbp[192 + 128 + jj];

  __shared__ float hs[2][64];
  __shared__ float xpb[2][16 * 192];  // 24 KB double-buffered xp chunks
  if (tid < 64) hs[0][tid] = 0.f;

  const float* xpr = xp + (size_t)(side * 16384 + b * 512) * 192;
  float* w0 = wh + ((size_t)(2 * side) * 16384 + b * 512) * 128 + 64 + jj;
  float* w1 = wh + ((size_t)(2 * side + 1) * 16384 + b * 512) * 128 + 64 + jj;

  // load chunk 0 directly
  {
    const float4* src = (const float4*)xpr;
    float4* dst = (float4*)xpb[0];
#pragma unroll
    for (int q = 0; q < 3; ++q) dst[q * 256 + tid] = src[q * 256 + tid];
  }
  __syncthreads();

  float hout[16];
  int cur = 0;
  for (int tc = 0; tc < 32; ++tc) {
    // issue prefetch of next chunk into registers (consumed at chunk end)
    float4 pf0, pf1, pf2;
    if (tc + 1 < 32) {
      const float4* src = (const float4*)(xpr + (size_t)(tc + 1) * 3072);
      pf0 = src[0 * 256 + tid];
      pf1 = src[1 * 256 + tid];
      pf2 = src[2 * 256 + tid];
    }
#pragma unroll
    for (int tt = 0; tt < 16; ++tt) {
      int t = tc * 16 + tt;
      int hb = t & 1;
      const float* hsrc = hs[hb];
      const float* xc = &xpb[cur][tt * 192];
      float cxz = xc[jj], cxr = xc[64 + jj], cxv = xc[128 + jj];
      float hold = hsrc[jj];
      const float4* h4 = (const float4*)(hsrc + 16 * ks);
      v2f az = {0.f, 0.f}, ar = {0.f, 0.f}, av = {0.f, 0.f};
#pragma unroll
      for (int c = 0; c < 4; ++c) {
        float4 h = h4[c];
        v2f hlo = {h.x, h.y}, hhi = {h.z, h.w};
        az = fma2(hlo, wz[2 * c], az);
        az = fma2(hhi, wz[2 * c + 1], az);
        ar = fma2(hlo, wr[2 * c], ar);
        ar = fma2(hhi, wr[2 * c + 1], ar);
        av = fma2(hlo, wv[2 * c], av);
        av = fma2(hhi, wv[2 * c + 1], av);
      }
      float saz = az.x + az.y, sar = ar.x + ar.y, sav = av.x + av.y;
      saz += __shfl_xor(saz, 16, 64);
      saz += __shfl_xor(saz, 32, 64);
      sar += __shfl_xor(sar, 16, 64);
      sar += __shfl_xor(sar, 32, 64);
      sav += __shfl_xor(sav, 16, 64);
      sav += __shfl_xor(sav, 32, 64);
      float z = sigm(cxz + saz + bz);
      float r = sigm(cxr + sar + brr);
      float hh = tanh_f(cxv + r * (sav + bv));
      float hnew = fmaf(z, hold - hh, hh);  // z*h + (1-z)*hh
      hout[tt] = hnew;
      if (ks == 0) hs[hb ^ 1][jj] = hnew;
      LDS_BARRIER();
    }
    // batched global stores (overlap next chunk; no barrier waits on them)
    if (ks == 0) {
      size_t ro = (size_t)(tc * 16) * 128;
#pragma unroll
      for (int tt = 0; tt < 16; ++tt) {
        float rv = fmaxf(hout[tt], 0.f);
        w0[ro + (size_t)tt * 128] = rv;
        w1[ro + (size_t)tt * 128] = rv;
      }
    }
    // write prefetched chunk into back buffer (reg deps enforce vm wait)
    if (tc + 1 < 32) {
      float4* dst = (float4*)xpb[cur ^ 1];
      dst[0 * 256 + tid] = pf0;
      dst[1 * 256 + tid] = pf1;
      dst[2 * 256 + tid] = pf2;
      LDS_BARRIER();
    }
    cur ^= 1;
  }
}

// ---------------------------------------------------------------------------
// CSR/CSC build, pass 1: counts.  grid 512 x 256.
__global__ __launch_bounds__(256, 1) void k_count(
    const float* __restrict__ A1, const float* __restrict__ A2,
    int* __restrict__ counts, int* __restrict__ ccolchunk) {
  int bid = blockIdx.x;
  int s = bid >> 8, b = (bid >> 3) & 31, ch = bid & 7;
  const float* A = s ? A2 : A1;
  const float4* A4 = (const float4*)(A + ((size_t)b * 512 + ch * 64) * 512);
  int t = threadIdx.x;
  __shared__ int ccol[512];
  __shared__ int crow[64];
  ccol[t] = 0;
  ccol[t + 256] = 0;
  if (t < 64) crow[t] = 0;
  __syncthreads();
#pragma unroll
  for (int it = 0; it < 32; ++it) {
    int idx = it * 256 + t;
    int r = idx >> 7, c4 = idx & 127;
    float4 v = A4[idx];
    int n = 0;
    if (v.x != 0.f) { atomicAdd(&ccol[4 * c4 + 0], 1); n++; }
    if (v.y != 0.f) { atomicAdd(&ccol[4 * c4 + 1], 1); n++; }
    if (v.z != 0.f) { atomicAdd(&ccol[4 * c4 + 2], 1); n++; }
    if (v.w != 0.f) { atomicAdd(&ccol[4 * c4 + 3], 1); n++; }
    if (n) atomicAdd(&crow[r], n);
  }
  __syncthreads();
  if (t < 64) counts[(2 * s) * 16384 + b * 512 + ch * 64 + t] = crow[t];
  int cbase = ((s * 32 + b) * 8 + ch) * 512;
  ccolchunk[cbase + t] = ccol[t];
  ccolchunk[cbase + t + 256] = ccol[t + 256];
}

// ---------------------------------------------------------------------------
// CSR/CSC build, pass 2: offsets. grid 256 x 256.
__global__ __launch_bounds__(256, 1) void k_alloc(
    const int* __restrict__ ccolchunk, int* __restrict__ counts,
    int* __restrict__ starts, int* __restrict__ chunkbase,
    int* __restrict__ cursors) {
  int bid = blockIdx.x;
  int t = threadIdx.x;
  int lane = t & 63, wave = t >> 6;
  __shared__ int wsum[4];
  __shared__ int gbase;

  int c, cursor_idx, out_idx;
  int pchunk[8];
  if (bid < 128) {
    int fr = bid * 256 + t;  // 0..32767
    int s = fr >> 14;
    out_idx = (2 * s) * 16384 + (fr & 16383);
    cursor_idx = 2 * s;
    c = counts[out_idx];
  } else {
    int cid = (bid - 128) * 256 + t;  // 0..32767 -> (s,b,j)
    int s = cid >> 14, b = (cid >> 9) & 31, j = cid & 511;
    out_idx = (2 * s + 1) * 16384 + b * 512 + j;
    cursor_idx = 2 * s + 1;
    c = 0;
#pragma unroll
    for (int ch = 0; ch < 8; ++ch) {
      pchunk[ch] = ccolchunk[((s * 32 + b) * 8 + ch) * 512 + j];
      c += pchunk[ch];
    }
    counts[out_idx] = c;
  }
  int v = c;
#pragma unroll
  for (int d = 1; d < 64; d <<= 1) {
    int o = __shfl_up(v, d, 64);
    if (lane >= d) v += o;
  }
  if (lane == 63) wsum[wave] = v;
  __syncthreads();
  int wbase = 0;
  for (int w = 0; w < wave; ++w) wbase += w < 4 ? wsum[w] : 0;
  int tot = wsum[0] + wsum[1] + wsum[2] + wsum[3];
  if (t == 0) gbase = atomicAdd(&cursors[cursor_idx], tot);
  __syncthreads();
  int start = gbase + wbase + v - c;
  starts[out_idx] = start;
  if (bid >= 128) {
    int cid = (bid - 128) * 256 + t;
    int s = cid >> 14, b = (cid >> 9) & 31, j = cid & 511;
    int run = start;
#pragma unroll
    for (int ch = 0; ch < 8; ++ch) {
      chunkbase[((s * 32 + b) * 8 + ch) * 512 + j] = run;
      run += pchunk[ch];
    }
  }
}

// ---------------------------------------------------------------------------
// CSR/CSC build, pass 3: fill. grid 512 x 256. LDS-atomic positions only.
__global__ __launch_bounds__(256, 1) void k_fill(
    const float* __restrict__ A1, const float* __restrict__ A2,
    const int* __restrict__ starts, const int* __restrict__ chunkbase,
    int* __restrict__ edges) {
  int bid = blockIdx.x;
  int s = bid >> 8, b = (bid >> 3) & 31, ch = bid & 7;
  const float* A = s ? A2 : A1;
  const float4* A4 = (const float4*)(A + ((size_t)b * 512 + ch * 64) * 512);
  int t = threadIdx.x;
  __shared__ int ccol[512];
  __shared__ int cb[512];
  __shared__ int crow[64];
  __shared__ int sf[64];
  ccol[t] = 0;
  ccol[t + 256] = 0;
  int cbase = ((s * 32 + b) * 8 + ch) * 512;
  cb[t] = chunkbase[cbase + t];
  cb[t + 256] = chunkbase[cbase + t + 256];
  if (t < 64) {
    crow[t] = 0;
    sf[t] = starts[(2 * s) * 16384 + b * 512 + ch * 64 + t];
  }
  __syncthreads();
  int* efwd = edges + (size_t)(2 * s) * CAP;
  int* erev = edges + (size_t)(2 * s + 1) * CAP;
#pragma unroll
  for (int it = 0; it < 32; ++it) {
    int idx = it * 256 + t;
    int r = idx >> 7, c4 = idx & 127;
    float4 v = A4[idx];
    float vv[4] = {v.x, v.y, v.z, v.w};
    int i = ch * 64 + r;
#pragma unroll
    for (int e = 0; e < 4; ++e) {
      if (vv[e] != 0.f) {
        int j = 4 * c4 + e;
        int lp = atomicAdd(&ccol[j], 1);
        int ri = cb[j] + lp;
        if (ri < CAP) erev[ri] = i;
        int fp = atomicAdd(&crow[r], 1);
        int fi = sf[r] + fp;
        if (fi < CAP) efwd[fi] = j;
      }
    }
  }
}

// ---------------------------------------------------------------------------
// whg = wh @ W_g;  ah1 = wh@a1_w + a1_b;  ah2 = wh@a2_w + a2_b
// grid 1024 x 64; one wave = 64 rows, packed-f32 acc, W_g via uniform loads.
__global__ __launch_bounds__(64, 1) void k_whg(
    const float* __restrict__ wh, const float* __restrict__ Wg,
    const float* __restrict__ a1w, const float* __restrict__ a1b,
    const float* __restrict__ a2w, const float* __restrict__ a2b,
    float* __restrict__ whg, float* __restrict__ ah1, float* __restrict__ ah2) {
  __shared__ float stage[64 * 129];
  int rowbase = blockIdx.x * 64;
  int tid = threadIdx.x;
  const float4* wh4 = (const float4*)(wh + (size_t)rowbase * 128);
#pragma unroll
  for (int p = 0; p < 32; ++p) {
    int s = p * 64 + tid;
    int r = s >> 5, q = s & 31;
    float4 v = wh4[r * 32 + q];
    stage[r * 129 + 4 * q + 0] = v.x;
    stage[r * 129 + 4 * q + 1] = v.y;
    stage[r * 129 + 4 * q + 2] = v.z;
    stage[r * 129 + 4 * q + 3] = v.w;
  }
  v2f acc[64];
#pragma unroll
  for (int c = 0; c < 64; ++c) acc[c] = (v2f){0.f, 0.f};
  float p1 = a1b[0], p2 = a2b[0];
  const float4* Wg4 = (const float4*)Wg;  // [128][32] f4
  for (int i = 0; i < 128; ++i) {
    float rv = stage[tid * 129 + i];
    v2f rv2 = {rv, rv};
    p1 = fmaf(rv, a1w[i], p1);
    p2 = fmaf(rv, a2w[i], p2);
#pragma unroll
    for (int c4 = 0; c4 < 32; ++c4) {
      float4 w = Wg4[i * 32 + c4];
      acc[2 * c4 + 0] = fma2(rv2, (v2f){w.x, w.y}, acc[2 * c4 + 0]);
      acc[2 * c4 + 1] = fma2(rv2, (v2f){w.z, w.w}, acc[2 * c4 + 1]);
    }
  }
  int grow = rowbase + tid;
  float4* o4 = (float4*)(whg + (size_t)grow * 128);
#pragma unroll
  for (int c4 = 0; c4 < 32; ++c4) {
    float4 o;
    o.x = acc[2 * c4].x;
    o.y = acc[2 * c4].y;
    o.z = acc[2 * c4 + 1].x;
    o.w = acc[2 * c4 + 1].y;
    o4[c4] = o;
  }
  ah1[grow] = p1;
  ah2[grow] = p2;
}

// ---------------------------------------------------------------------------
// Per-row edge softmax + aggregate + elu update. One WAVE per row.
// grid 65536 x 64. No barriers (single-wave LDS program order).
__global__ __launch_bounds__(64, 1) void k_attn(
    float* __restrict__ wh, const float* __restrict__ whg,
    const float* __restrict__ ah1, const float* __restrict__ ah2,
    const int* __restrict__ starts, const int* __restrict__ counts,
    const int* __restrict__ edges) {
  int row = blockIdx.x;
  int st = row >> 14;
  int base = row & ~511;
  int t = threadIdx.x;
  __shared__ int jl[512];
  __shared__ float el[512];
  int start = starts[row], cnt = counts[row];
  const int* ed = edges + (size_t)st * CAP + start;
  float a1v = ah1[row];
  const float* ah2b = ah2 + base;
  float lmax = -1e30f;
  for (int k = t; k < cnt; k += 64) {
    int jj = ed[k];
    float e = a1v + ah2b[jj];
    e = e >= 0.f ? e : 0.2f * e;  // leaky_relu 0.2
    jl[k] = jj;
    el[k] = e;
    lmax = fmaxf(lmax, e);
  }
#pragma unroll
  for (int off = 32; off; off >>= 1) lmax = fmaxf(lmax, __shfl_xor(lmax, off, 64));
  float lsum = 0.f;
  for (int k = t; k < cnt; k += 64) {
    float w = __expf(el[k] - lmax);
    el[k] = w;
    lsum += w;
  }
#pragma unroll
  for (int off = 32; off; off >>= 1) lsum += __shfl_xor(lsum, off, 64);
  float inv = cnt > 0 ? 1.0f / lsum : 0.f;
  // gather: lane t owns dims t and t+64; 2 edges in flight
  float a0 = 0.f, a1 = 0.f, b0 = 0.f, b1 = 0.f;
  const float* wgb = whg + (size_t)base * 128;
  int k = 0;
  for (; k + 2 <= cnt; k += 2) {
    float w0 = el[k], w1 = el[k + 1];
    const float* p0 = wgb + (size_t)jl[k] * 128;
    const float* p1 = wgb + (size_t)jl[k + 1] * 128;
    a0 = fmaf(w0, p0[t], a0);
    b0 = fmaf(w0, p0[t + 64], b0);
    a1 = fmaf(w1, p1[t], a1);
    b1 = fmaf(w1, p1[t + 64], b1);
  }
  if (k < cnt) {
    float w0 = el[k];
    const float* p0 = wgb + (size_t)jl[k] * 128;
    a0 = fmaf(w0, p0[t], a0);
    b0 = fmaf(w0, p0[t + 64], b0);
  }
  float accl = (a0 + a1) * inv, acch = (b0 + b1) * inv;
  float* wr = wh + (size_t)row * 128;
  float v0 = wr[t] + accl;
  wr[t] = v0 > 0.f ? v0 : __expf(v0) - 1.f;  // elu
  float v1 = wr[t + 64] + acch;
  wr[t + 64] = v1 > 0.f ? v1 : __expf(v1) - 1.f;
}

// ---------------------------------------------------------------------------
// mid[side][b][c] = sum_i (wh[2s][b][i][c] + wh[2s+1][b][i][c]). grid 512x256.
__global__ void k_mid(const float* __restrict__ wh, float* __restrict__ mid) {
  int blk = blockIdx.x;
  int side = blk >> 8, b = (blk >> 3) & 31, ch = blk & 7;
  int t = threadIdx.x;
  int c = t & 127, hh = t >> 7;
  float sum = 0.f;
  size_t b0 = ((size_t)(2 * side) * 16384 + b * 512) * 128;
  size_t b1 = ((size_t)(2 * side + 1) * 16384 + b * 512) * 128;
  for (int q = 0; q < 32; ++q) {
    int i = ch * 64 + hh * 32 + q;
    sum += wh[b0 + (size_t)i * 128 + c];
    sum += wh[b1 + (size_t)i * 128 + c];
  }
  atomicAdd(&mid[(side * 32 + b) * 128 + c], sum);
}

__global__ void k_out(const float* __restrict__ mid,
                      const float* __restrict__ Wout,
                      const float* __restrict__ bout, float* __restrict__ e12) {
  int sb = blockIdx.x;  // 0..63  (side*32+b)
  int o = threadIdx.x;  // 0..63
  const float* m = mid + sb * 128;
  float acc = bout[o];
  for (int k = 0; k < 128; ++k) acc = fmaf(m[k], Wout[k * 64 + o], acc);
  e12[sb * 64 + o] = acc;
}

__global__ void k_cos(const float* __restrict__ e12, float* __restrict__ out) {
  int b = threadIdx.x;
  if (b >= 32) return;
  const float* e1 = e12 + b * 64;
  const float* e2 = e12 + 2048 + b * 64;
  float d = 0.f, n1 = 0.f, n2 = 0.f;
  for (int o = 0; o < 64; ++o) {
    float a = e1[o], c = e2[o];
    d = fmaf(a, c, d);
    n1 = fmaf(a, a, n1);
    n2 = fmaf(c, c, n2);
  }
  float nn = fmaxf(sqrtf(n1), 1e-12f) * fmaxf(sqrtf(n2), 1e-12f);
  out[b] = 0.5f * (1.f + d / nn);
}

// ---------------------------------------------------------------------------
extern "C" void kernel_launch(void* const* d_in, const int* in_sizes, int n_in,
                              void* d_out, int out_size, void* d_ws,
                              size_t ws_size, hipStream_t stream) {
  const float* CFG1 = (const float*)d_in[0];
  const float* LIT1 = (const float*)d_in[2];
  const float* SEM1 = (const float*)d_in[3];
  const float* CFG2 = (const float*)d_in[4];
  const float* LIT2 = (const float*)d_in[6];
  const float* SEM2 = (const float*)d_in[7];
  const float* WL1 = (const float*)d_in[8];
  const float* GK1 = (const float*)d_in[9];
  const float* GRK1 = (const float*)d_in[10];
  const float* GB1 = (const float*)d_in[11];
  const float* WL2 = (const float*)d_in[12];
  const float* GK2 = (const float*)d_in[13];
  const float* GRK2 = (const float*)d_in[14];
  const float* GB2 = (const float*)d_in[15];
  const float* A1W = (const float*)d_in[16];
  const float* A1B = (const float*)d_in[17];
  const float* A2W = (const float*)d_in[18];
  const float* A2B = (const float*)d_in[19];
  const float* WG = (const float*)d_in[20];
  const float* WOUT = (const float*)d_in[21];
  const float* BOUT = (const float*)d_in[22];

  float* ws = (float*)d_ws;
  float* wh = ws;             // 8388608
  float* whg = wh + 8388608;  // 8388608 (xp aliases; tail aliases csr scratch)
  float* xp = whg;            // [2][16384][192] = 6291456 < 8388608
  int* ccolchunk = (int*)(whg + 6291456);  // 262144
  int* chunkbase = ccolchunk + 262144;     // 262144
  float* spare = whg + 8388608;            // 4194304 (unused)
  float* ah1 = spare + 4194304;            // 65536
  float* ah2 = ah1 + 65536;                // 65536
  float* mid = ah2 + 65536;                // 8192
  float* e12 = mid + 8192;                 // 4096
  int* starts = (int*)(e12 + 4096);        // 65536
  int* counts = starts + 65536;            // 65536
  int* cursors = counts + 65536;           // 64
  int* edges = cursors + 64;               // 4*CAP

  hipMemsetAsync(cursors, 0, 64 * 4, stream);
  hipMemsetAsync(mid, 0, 8192 * 4, stream);

  k_data<<<1024, 64, 0, stream>>>(LIT1, SEM1, LIT2, SEM2, WL1, GK1, GB1, WL2,
                                  GK2, GB2, wh, xp);
  k_gru<<<64, 256, 0, stream>>>(xp, GRK1, GB1, GRK2, GB2, wh);
  k_count<<<512, 256, 0, stream>>>(CFG1, CFG2, counts, ccolchunk);
  k_alloc<<<256, 256, 0, stream>>>(ccolchunk, counts, starts, chunkbase,
                                   cursors);
  k_fill<<<512, 256, 0, stream>>>(CFG1, CFG2, starts, chunkbase, edges);
  for (int step = 0; step < 3; ++step) {
    k_whg<<<1024, 64, 0, stream>>>(wh, WG, A1W, A1B, A2W, A2B, whg, ah1, ah2);
    k_attn<<<65536, 64, 0, stream>>>(wh, whg, ah1, ah2, starts, counts, edges);
  }
  k_mid<<<512, 256, 0, stream>>>(wh, mid);
  k_out<<<64, 64, 0, stream>>>(mid, WOUT, BOUT, e12);
  k_cos<<<1, 64, 0, stream>>>(e12, (float*)d_out);
}